// Round 11
// baseline (1642.222 us; speedup 1.0000x reference)
//
#include <hip/hip_runtime.h>
#include <cstdint>
#include <cstddef>

typedef __attribute__((ext_vector_type(8))) short short8;     // 8 x 16-bit (4 VGPRs)
typedef __attribute__((ext_vector_type(8))) _Float16 f16x8;   // fp16 MFMA frag
typedef __attribute__((ext_vector_type(4))) float f32x4;
typedef __attribute__((ext_vector_type(4))) unsigned short u16x4;
typedef unsigned short u16;

#define FP_  2048
#define AD_  1024
#define BB_  512
#define TT_  50000
#define BETA_ 0.125f

// ---------- fp32 -> bf16 (RNE) helpers ----------
__device__ __forceinline__ u16 f2bf(float x){
  uint32_t u = __builtin_bit_cast(uint32_t, x);
  u = (u + 0x7fffu + ((u >> 16) & 1u)) >> 16;
  return (u16)u;
}
__device__ __forceinline__ float bf2f(u16 h){
  uint32_t u = ((uint32_t)h) << 16;
  return __builtin_bit_cast(float, u);
}
__device__ __forceinline__ u16 f2h_bits(float x){
  _Float16 h = (_Float16)x;            // RNE
  return __builtin_bit_cast(u16, h);
}
__device__ __forceinline__ unsigned int pkrtz_u32(float a, float b){
  return __builtin_bit_cast(unsigned int, __builtin_amdgcn_cvt_pkrtz(a, b));
}

// ---------- async global->LDS, 16B per lane ----------
__device__ __forceinline__ void gload_lds16(const void* g, void* l){
  __builtin_amdgcn_global_load_lds((const __attribute__((address_space(1))) void*)g,
                                   (__attribute__((address_space(3))) void*)l,
                                   16, 0, 0);
}

#define SB   __builtin_amdgcn_s_barrier()
#define SCH  __builtin_amdgcn_sched_barrier(0)
#define WAIT_LGKM0 asm volatile("s_waitcnt lgkmcnt(0)" ::: "memory")
#define WAIT_VM(n) asm volatile("s_waitcnt vmcnt(" #n ")" ::: "memory")

// ---------- elementwise fp32 -> (hi,lo) bf16 ----------
__global__ void conv_hilo_k(const float* __restrict__ src, u16* __restrict__ hi,
                            u16* __restrict__ lo, int n){
  int i = (blockIdx.x * blockDim.x + threadIdx.x) * 4;
  if (i >= n) return;
  f32x4 v = *reinterpret_cast<const f32x4*>(src + i);
  u16x4 h, l;
  #pragma unroll
  for (int e = 0; e < 4; ++e){
    float x = v[e];
    u16 hs = f2bf(x);
    h[e] = hs;
    l[e] = f2bf(x - bf2f(hs));
  }
  *reinterpret_cast<u16x4*>(hi + i) = h;
  *reinterpret_cast<u16x4*>(lo + i) = l;
}

// ---------- W[R][C] -> out[C][R] with hi/lo split (LDS tile transpose) ----------
__global__ void conv_hilo_T_k(const float* __restrict__ W, u16* __restrict__ hiT,
                              u16* __restrict__ loT, int R, int C){
  __shared__ float tile[32][33];
  int c0 = blockIdx.x * 32;
  int r0 = blockIdx.y * 32;
  int tx = threadIdx.x;   // 0..31
  int ty = threadIdx.y;   // 0..7
  #pragma unroll
  for (int i = 0; i < 32; i += 8)
    tile[ty + i][tx] = W[(size_t)(r0 + ty + i) * C + c0 + tx];
  __syncthreads();
  #pragma unroll
  for (int i = 0; i < 32; i += 8){
    float x = tile[tx][ty + i];              // = W[r0+tx][c0+ty+i]
    u16 hs = f2bf(x);
    size_t o = (size_t)(c0 + ty + i) * R + r0 + tx;   // out[f][a]
    hiT[o] = hs;
    loT[o] = f2bf(x - bf2f(hs));
  }
}

// ---------- c[b] = dot(Xi[b,:], b_temp) : one wave per row ----------
__global__ void dot_rows_k(const float* __restrict__ Xi, const float* __restrict__ bt,
                           float* __restrict__ c, int K){
  int row  = blockIdx.x * 4 + (threadIdx.x >> 6);
  int lane = threadIdx.x & 63;
  float s = 0.f;
  for (int a = lane; a < K; a += 64) s += Xi[(size_t)row * K + a] * bt[a];
  #pragma unroll
  for (int off = 32; off; off >>= 1) s += __shfl_down(s, off);
  if (lane == 0) c[row] = s;
}

// ---------- split-bf16 small GEMM: C = A·B^T + colBias (3-term hi/lo) ----------
// OUT16: 0=none, 1=bf16 hi/lo pair, 2=fp16 hi/lo pair
template<int TM, int TN, int FM, int FN, int OUT16>
__global__ __launch_bounds__(256, 2)
void gemm_hilo(const u16* __restrict__ Ahi, const u16* __restrict__ Alo,
               const u16* __restrict__ Bhi, const u16* __restrict__ Blo,
               int M, int N, int K,
               float* __restrict__ Cf, u16* __restrict__ Chi, u16* __restrict__ Clo,
               const float* __restrict__ colBias)
{
  constexpr int BK = 32;
  constexpr int WM = TM / (16 * FM);
  constexpr int WN = TN / (16 * FN);
  static_assert(WM * WN == 4, "4 waves / 256 threads");
  constexpr int BUFE = (2 * TM + 2 * TN) * BK;

  __shared__ __align__(16) u16 lds[2 * BUFE];

  const int m0 = blockIdx.x * TM;
  const int n0 = blockIdx.y * TN;

  const int tid  = threadIdx.x;
  const int w    = tid >> 6;
  const int lane = tid & 63;
  const int lr   = lane & 15;
  const int lg   = lane >> 4;
  const int wm   = w / WN;
  const int wn   = w % WN;

  const int rrA = tid >> 2;     // 0..63
  const int chA = tid & 3;      // 16B chunk

  short8 ra[2], rb[2];

  f32x4 acc[FM][FN];
  #pragma unroll
  for (int i = 0; i < FM; ++i)
    #pragma unroll
    for (int j = 0; j < FN; ++j)
      acc[i][j] = (f32x4){0.f, 0.f, 0.f, 0.f};

  auto stage_load = [&](int k0){
    int gm = m0 + rrA;
    ra[0] = *reinterpret_cast<const short8*>(Ahi + (size_t)gm * K + k0 + chA * 8);
    ra[1] = *reinterpret_cast<const short8*>(Alo + (size_t)gm * K + k0 + chA * 8);
    int gn = n0 + rrA; if (gn > N - 1) gn = N - 1;
    rb[0] = *reinterpret_cast<const short8*>(Bhi + (size_t)gn * K + k0 + chA * 8);
    rb[1] = *reinterpret_cast<const short8*>(Blo + (size_t)gn * K + k0 + chA * 8);
  };
  auto stage_store = [&](int buf){
    u16* As_hi = lds + buf * BUFE;
    u16* As_lo = As_hi + TM * BK;
    u16* Bs_hi = As_hi + 2 * TM * BK;
    u16* Bs_lo = As_hi + 2 * TM * BK + TN * BK;
    int row = rrA;
    int sw  = (chA ^ ((row >> 1) & 3)) << 3;
    *reinterpret_cast<short8*>(As_hi + row * BK + sw) = ra[0];
    *reinterpret_cast<short8*>(As_lo + row * BK + sw) = ra[1];
    *reinterpret_cast<short8*>(Bs_hi + row * BK + sw) = rb[0];
    *reinterpret_cast<short8*>(Bs_lo + row * BK + sw) = rb[1];
  };

  const int NT = K / BK;
  stage_load(0);
  stage_store(0);
  __syncthreads();

  int cur = 0;
  for (int t = 0; t < NT; ++t){
    const bool have_next = (t + 1 < NT);
    if (have_next) stage_load((t + 1) * BK);

    u16* As_hi = lds + cur * BUFE;
    u16* As_lo = As_hi + TM * BK;
    u16* Bs_hi = As_hi + 2 * TM * BK;
    u16* Bs_lo = As_hi + 2 * TM * BK + TN * BK;

    short8 ah[FM], al[FM], bh[FN], bl[FN];
    #pragma unroll
    for (int i = 0; i < FM; ++i){
      int row = wm * FM * 16 + i * 16 + lr;
      int off = row * BK + ((lg ^ ((row >> 1) & 3)) << 3);
      ah[i] = *reinterpret_cast<short8*>(As_hi + off);
      al[i] = *reinterpret_cast<short8*>(As_lo + off);
    }
    #pragma unroll
    for (int j = 0; j < FN; ++j){
      int row = wn * FN * 16 + j * 16 + lr;
      int off = row * BK + ((lg ^ ((row >> 1) & 3)) << 3);
      bh[j] = *reinterpret_cast<short8*>(Bs_hi + off);
      bl[j] = *reinterpret_cast<short8*>(Bs_lo + off);
    }
    #pragma unroll
    for (int i = 0; i < FM; ++i)
      #pragma unroll
      for (int j = 0; j < FN; ++j){
        acc[i][j] = __builtin_amdgcn_mfma_f32_16x16x32_bf16(ah[i], bh[j], acc[i][j], 0, 0, 0);
        acc[i][j] = __builtin_amdgcn_mfma_f32_16x16x32_bf16(ah[i], bl[j], acc[i][j], 0, 0, 0);
        acc[i][j] = __builtin_amdgcn_mfma_f32_16x16x32_bf16(al[i], bh[j], acc[i][j], 0, 0, 0);
      }

    if (have_next){
      __builtin_amdgcn_sched_barrier(0);
      stage_store(cur ^ 1);
      __syncthreads();
    }
    cur ^= 1;
  }

  #pragma unroll
  for (int i = 0; i < FM; ++i){
    int rbase = m0 + wm * FM * 16 + i * 16 + lg * 4;
    #pragma unroll
    for (int j = 0; j < FN; ++j){
      int gcol = n0 + wn * FN * 16 + j * 16 + lr;
      if (gcol < N){
        float cb = colBias ? colBias[gcol] : 0.f;
        #pragma unroll
        for (int r = 0; r < 4; ++r){
          int grow = rbase + r;
          float v = acc[i][j][r] + cb;
          size_t idx = (size_t)grow * N + gcol;
          if (Cf) Cf[idx] = v;
          if constexpr (OUT16 == 1){
            u16 hs = f2bf(v);
            Chi[idx] = hs;
            Clo[idx] = f2bf(v - bf2f(hs));
          } else if constexpr (OUT16 == 2){
            _Float16 h = (_Float16)v;
            Chi[idx] = __builtin_bit_cast(u16, h);
            Clo[idx] = f2h_bits(v - (float)h);
          }
        }
      }
    }
  }
}

// ---------- BIG GEMM, streaming-B regime: R6 structure at 6 blocks/CU ----------
// out = alpha*(A·B^T + rowAdd); A = Y fp16 [512][2048] (L2-resident),
// B = fp32 templates converted to fp16 in the staging path (HBM stream).
// TM=64 x TN=128, BK=32, 4 waves (2x2, wave tile 32x64), LDS dbuf 24KB.
// 6 blocks/CU (144KB LDS, VGPR cap 85 -- R6 compiled to 60): 24 waves/CU of
// INDEPENDENT blocks overlap each other's per-iter latency chains.
// B prefetched 2 tiles ahead into regs (rbE/rbO); A 1 ahead via gload_lds.
// Per-wave vmcnt ledger at steady iter t: [B(t+1):4, A(t+1):1, B(t+2):4]=9
//   post-MFMA: vmcnt(5) -> B(t+1) ready; convert+ds_write; vmcnt(4) -> A(t+1)
//   landed; lgkm0; ONE s_barrier per iter. Tail: vmcnt(1)/vmcnt(0).
__global__ __launch_bounds__(256, 6)
void gemm_big(const u16* __restrict__ Ah,      // fp16 bits [512][2048]
              const float* __restrict__ Bf,    // [50000][2048]
              float* __restrict__ C,
              const float* __restrict__ rowAdd, float alpha)
{
  constexpr int TM = 64, TN = 128, BK = 32;
  constexpr int K = FP_, NN = TT_;
  constexpr int NT = K / BK;                 // 64
  constexpr int SLOT_A = TM * BK;            // 2048 u16 = 4KB
  constexpr int BUFE   = SLOT_A + TN * BK;   // 6144 u16 = 12KB

  __shared__ __align__(16) u16 lds[2 * BUFE];   // 24KB

  // bijective XCD grouping: xcd<7 own 49 N-strips, xcd=7 owns 48 (391 total).
  // g = s*8 + mt -> the 8 M-blocks of a strip run concurrently on one XCD.
  int id  = blockIdx.x;
  int xcd = id & 7;
  int g   = id >> 3;          // 0..391
  int mt  = g & 7;            // 8 M-tiles of 64
  int s   = g >> 3;           // 0..48
  int strips = (xcd < 7) ? 49 : 48;
  if (s >= strips) return;
  int nt = ((xcd < 7) ? xcd * 49 : 343) + s;   // 0..390
  const int m0 = mt * TM;
  const int n0 = nt * TN;

  const int tid  = threadIdx.x;
  const int w    = tid >> 6;        // 0..3
  const int lane = tid & 63;
  const int lr   = lane & 15;
  const int lg   = lane >> 4;
  const int wm   = w >> 1;          // 0..1  (32-row band)
  const int wn   = w & 1;           // 0..1  (64-col band)

  const int rowB = tid >> 3;        // 0..31
  const int c4   = tid & 7;         // f32x4 chunk in a 32-float row

  // ---- staging helpers ----
  auto issueA = [&](int k0, u16* sp){          // 1 vmcnt entry per wave
    int rloc = lane >> 2;                      // 0..15
    int cc   = lane & 3;
    int row  = w * 16 + rloc;
    int sc   = cc ^ ((row >> 1) & 3);          // inverse swizzle on source
    const u16* gh = Ah + (size_t)(m0 + row) * K + k0 + sc * 8;
    gload_lds16(gh, sp + w * 16 * BK);         // wave-uniform dest + lane*16B
  };
  auto issueB = [&](int k0, f32x4 (&rb)[4]){   // 4 vmcnt entries per wave
    #pragma unroll
    for (int p = 0; p < 4; ++p){
      int gn = n0 + rowB + p * 32; if (gn > NN - 1) gn = NN - 1;
      rb[p] = *reinterpret_cast<const f32x4*>(Bf + (size_t)gn * K + k0 + c4 * 4);
    }
  };
  auto writeB = [&](u16* sp, f32x4 (&rb)[4]){
    u16* bb = sp + SLOT_A;
    #pragma unroll
    for (int p = 0; p < 4; ++p){
      int row = rowB + p * 32;
      uint2 hv;
      hv.x = pkrtz_u32(rb[p][0], rb[p][1]);
      hv.y = pkrtz_u32(rb[p][2], rb[p][3]);
      int q   = c4 >> 1;
      int off = row * BK + ((q ^ ((row >> 1) & 3)) << 3) + (c4 & 1) * 4;
      *reinterpret_cast<uint2*>(bb + off) = hv;
    }
  };

  f32x4 acc[2][4];
  #pragma unroll
  for (int i = 0; i < 2; ++i)
    #pragma unroll
    for (int j = 0; j < 4; ++j)
      acc[i][j] = (f32x4){0.f, 0.f, 0.f, 0.f};

  f32x4 rbE[4], rbO[4];

  // ---- prologue: A(0), B(0), B(1); publish tile 0 ----
  issueA(0, lds);            // 1
  issueB(0, rbE);            // 4
  issueB(BK, rbO);           // 4     queue: [A0:1, B0:4, B1:4] = 9
  SCH;
  WAIT_VM(4);                // A0 + B0 retired (remain B1:4)
  writeB(lds, rbE);
  WAIT_LGKM0;
  SB; SCH;

  // ---- body: one barrier per iter; compute tile t, publish t+1, issue t+2 ----
  auto body = [&](int t, f32x4 (&rbFill)[4], f32x4 (&rbPub)[4]){
    u16* sp  = lds + (t & 1) * BUFE;
    u16* spn = lds + ((t + 1) & 1) * BUFE;
    if (t + 1 < NT) issueA((t + 1) * BK, spn);
    if (t + 2 < NT) issueB((t + 2) * BK, rbFill);

    f16x8 a[2], b[4];
    #pragma unroll
    for (int i = 0; i < 2; ++i){
      int row = wm * 32 + i * 16 + lr;
      int off = row * BK + ((lg ^ ((row >> 1) & 3)) << 3);
      a[i] = __builtin_bit_cast(f16x8, *reinterpret_cast<short8*>(sp + off));
    }
    #pragma unroll
    for (int j = 0; j < 4; ++j){
      int row = wn * 64 + j * 16 + lr;
      int off = row * BK + ((lg ^ ((row >> 1) & 3)) << 3);
      b[j] = __builtin_bit_cast(f16x8, *reinterpret_cast<short8*>(sp + SLOT_A + off));
    }
    WAIT_LGKM0; SCH;
    #pragma unroll
    for (int i = 0; i < 2; ++i)
      #pragma unroll
      for (int j = 0; j < 4; ++j)
        acc[i][j] = __builtin_amdgcn_mfma_f32_16x16x32_f16(a[i], b[j], acc[i][j], 0, 0, 0);
    SCH;

    if (t + 2 < NT){
      WAIT_VM(5);            // B(t+1) retired (leaves A(t+1):1, B(t+2):4)
      writeB(spn, rbPub);
      WAIT_VM(4);            // A(t+1) landed  (leaves B(t+2):4)
      WAIT_LGKM0;
    } else if (t + 1 < NT){
      WAIT_VM(1);            // B(NT-1) retired (leaves A(NT-1):1)
      writeB(spn, rbPub);
      WAIT_VM(0);            // A(NT-1) landed
      WAIT_LGKM0;
    }
    SB; SCH;
  };

  for (int tt = 0; tt < NT; tt += 2){
    body(tt,     rbE, rbO);   // fills rbE with B(tt+2), publishes B(tt+1) from rbO
    body(tt + 1, rbO, rbE);   // fills rbO with B(tt+3), publishes B(tt+2) from rbE
  }

  // ---- epilogue: row=(lane>>4)*4+reg (A index), col=lane&15 (B index) ----
  #pragma unroll
  for (int i = 0; i < 2; ++i){
    int rbase = m0 + wm * 32 + i * 16 + lg * 4;
    #pragma unroll
    for (int j = 0; j < 4; ++j){
      int gcol = n0 + wn * 64 + j * 16 + lr;
      if (gcol < NN){
        #pragma unroll
        for (int r = 0; r < 4; ++r){
          int grow = rbase + r;
          float v = (acc[i][j][r] + rowAdd[grow]) * alpha;
          C[(size_t)grow * NN + gcol] = v;
        }
      }
    }
  }
}

extern "C" void kernel_launch(void* const* d_in, const int* in_sizes, int n_in,
                              void* d_out, int out_size, void* d_ws, size_t ws_size,
                              hipStream_t stream){
  (void)in_sizes; (void)n_in; (void)out_size; (void)ws_size;
  const float* m    = (const float*)d_in[0];   // [512][2048]
  const float* tpl  = (const float*)d_in[1];   // [50000][2048]
  const float* Wmol = (const float*)d_in[2];   // [1024][2048]
  const float* bmol = (const float*)d_in[3];   // [1024]
  const float* Wtmp = (const float*)d_in[4];   // [1024][2048]
  const float* btmp = (const float*)d_in[5];   // [1024]
  float* out = (float*)d_out;                  // [512][50000]

  uint8_t* wp = (uint8_t*)d_ws;
  auto carve = [&](size_t bytes) -> void* {
    void* p = (void*)wp;
    wp += (bytes + 255) & ~(size_t)255;
    return p;
  };
  u16* m_hi   = (u16*)carve((size_t)BB_ * FP_ * 2);
  u16* m_lo   = (u16*)carve((size_t)BB_ * FP_ * 2);
  u16* wm_hi  = (u16*)carve((size_t)AD_ * FP_ * 2);
  u16* wm_lo  = (u16*)carve((size_t)AD_ * FP_ * 2);
  u16* wtT_hi = (u16*)carve((size_t)FP_ * AD_ * 2);
  u16* wtT_lo = (u16*)carve((size_t)FP_ * AD_ * 2);
  float* Xi   = (float*)carve((size_t)BB_ * AD_ * 4);
  u16* Xi_hi  = (u16*)carve((size_t)BB_ * AD_ * 2);
  u16* Xi_lo  = (u16*)carve((size_t)BB_ * AD_ * 2);
  u16* Y_hi   = (u16*)carve((size_t)BB_ * FP_ * 2);   // fp16 bits
  u16* Y_lo   = (u16*)carve((size_t)BB_ * FP_ * 2);   // fp16 bits (unused by big gemm)
  float* cvec = (float*)carve((size_t)BB_ * 4);

  // 1) split inputs to bf16 hi/lo (W_temp also transposed to [FP][A])
  conv_hilo_k<<<(BB_ * FP_ / 4 + 255) / 256, 256, 0, stream>>>(m, m_hi, m_lo, BB_ * FP_);
  conv_hilo_k<<<(AD_ * FP_ / 4 + 255) / 256, 256, 0, stream>>>(Wmol, wm_hi, wm_lo, AD_ * FP_);
  conv_hilo_T_k<<<dim3(FP_ / 32, AD_ / 32), dim3(32, 8), 0, stream>>>(Wtmp, wtT_hi, wtT_lo, AD_, FP_);

  // 2) Xi = m @ W_mol^T + b_mol   [512 x 1024], K=2048  (fp32 + bf16 hi/lo out)
  gemm_hilo<64, 64, 2, 2, 1><<<dim3(BB_ / 64, AD_ / 64), 256, 0, stream>>>(
      m_hi, m_lo, wm_hi, wm_lo, BB_, AD_, FP_,
      Xi, Xi_hi, Xi_lo, bmol);

  // 3) c[b] = Xi[b,:] . b_temp
  dot_rows_k<<<BB_ / 4, 256, 0, stream>>>(Xi, btmp, cvec, AD_);

  // 4) Y = Xi @ W_temp   [512 x 2048], K=1024  -> fp16 hi/lo (big gemm uses hi only)
  gemm_hilo<64, 64, 2, 2, 2><<<dim3(BB_ / 64, FP_ / 64), 256, 0, stream>>>(
      Xi_hi, Xi_lo, wtT_hi, wtT_lo, BB_, FP_, AD_,
      nullptr, Y_hi, Y_lo, nullptr);

  // 5) out = BETA * (Y @ templates^T + c)   [512 x 50000], K=2048
  //    3136 blocks = 8 XCD x 49 strip-slots x 8 M-tiles; 8 masked. 6 blocks/CU.
  gemm_big<<<3136, 256, 0, stream>>>(Y_hi, tpl, out, cvec, BETA_);
}

// Round 12
// 989.479 us; speedup vs baseline: 1.6597x; 1.6597x over previous
//
#include <hip/hip_runtime.h>
#include <cstdint>
#include <cstddef>

typedef __attribute__((ext_vector_type(8))) short short8;     // 8 x 16-bit (4 VGPRs)
typedef __attribute__((ext_vector_type(8))) _Float16 f16x8;   // fp16 MFMA frag
typedef __attribute__((ext_vector_type(4))) float f32x4;
typedef __attribute__((ext_vector_type(4))) unsigned short u16x4;
typedef __attribute__((ext_vector_type(4))) unsigned int u32x4;
typedef unsigned short u16;

#define FP_  2048
#define AD_  1024
#define BB_  512
#define TT_  50000
#define BETA_ 0.125f

// ---------- fp32 -> bf16 (RNE) helpers ----------
__device__ __forceinline__ u16 f2bf(float x){
  uint32_t u = __builtin_bit_cast(uint32_t, x);
  u = (u + 0x7fffu + ((u >> 16) & 1u)) >> 16;
  return (u16)u;
}
__device__ __forceinline__ float bf2f(u16 h){
  uint32_t u = ((uint32_t)h) << 16;
  return __builtin_bit_cast(float, u);
}
__device__ __forceinline__ u16 f2h_bits(float x){
  _Float16 h = (_Float16)x;            // RNE
  return __builtin_bit_cast(u16, h);
}
__device__ __forceinline__ unsigned int pkrtz_u32(float a, float b){
  return __builtin_bit_cast(unsigned int, __builtin_amdgcn_cvt_pkrtz(a, b));
}

#define SCH  __builtin_amdgcn_sched_barrier(0)
#define WAIT_VM(n) asm volatile("s_waitcnt vmcnt(" #n ")" ::: "memory")

// ---------- elementwise fp32 -> (hi,lo) bf16 ----------
__global__ void conv_hilo_k(const float* __restrict__ src, u16* __restrict__ hi,
                            u16* __restrict__ lo, int n){
  int i = (blockIdx.x * blockDim.x + threadIdx.x) * 4;
  if (i >= n) return;
  f32x4 v = *reinterpret_cast<const f32x4*>(src + i);
  u16x4 h, l;
  #pragma unroll
  for (int e = 0; e < 4; ++e){
    float x = v[e];
    u16 hs = f2bf(x);
    h[e] = hs;
    l[e] = f2bf(x - bf2f(hs));
  }
  *reinterpret_cast<u16x4*>(hi + i) = h;
  *reinterpret_cast<u16x4*>(lo + i) = l;
}

// ---------- W[R][C] -> out[C][R] with hi/lo split (LDS tile transpose) ----------
__global__ void conv_hilo_T_k(const float* __restrict__ W, u16* __restrict__ hiT,
                              u16* __restrict__ loT, int R, int C){
  __shared__ float tile[32][33];
  int c0 = blockIdx.x * 32;
  int r0 = blockIdx.y * 32;
  int tx = threadIdx.x;   // 0..31
  int ty = threadIdx.y;   // 0..7
  #pragma unroll
  for (int i = 0; i < 32; i += 8)
    tile[ty + i][tx] = W[(size_t)(r0 + ty + i) * C + c0 + tx];
  __syncthreads();
  #pragma unroll
  for (int i = 0; i < 32; i += 8){
    float x = tile[tx][ty + i];              // = W[r0+tx][c0+ty+i]
    u16 hs = f2bf(x);
    size_t o = (size_t)(c0 + ty + i) * R + r0 + tx;   // out[f][a]
    hiT[o] = hs;
    loT[o] = f2bf(x - bf2f(hs));
  }
}

// ---------- c[b] = dot(Xi[b,:], b_temp) : one wave per row ----------
__global__ void dot_rows_k(const float* __restrict__ Xi, const float* __restrict__ bt,
                           float* __restrict__ c, int K){
  int row  = blockIdx.x * 4 + (threadIdx.x >> 6);
  int lane = threadIdx.x & 63;
  float s = 0.f;
  for (int a = lane; a < K; a += 64) s += Xi[(size_t)row * K + a] * bt[a];
  #pragma unroll
  for (int off = 32; off; off >>= 1) s += __shfl_down(s, off);
  if (lane == 0) c[row] = s;
}

// ---------- split-bf16 small GEMM: C = A·B^T + colBias (3-term hi/lo) ----------
// OUT16: 0=none, 1=bf16 hi/lo pair, 2=fp16 hi/lo pair
template<int TM, int TN, int FM, int FN, int OUT16>
__global__ __launch_bounds__(256, 2)
void gemm_hilo(const u16* __restrict__ Ahi, const u16* __restrict__ Alo,
               const u16* __restrict__ Bhi, const u16* __restrict__ Blo,
               int M, int N, int K,
               float* __restrict__ Cf, u16* __restrict__ Chi, u16* __restrict__ Clo,
               const float* __restrict__ colBias)
{
  constexpr int BK = 32;
  constexpr int WM = TM / (16 * FM);
  constexpr int WN = TN / (16 * FN);
  static_assert(WM * WN == 4, "4 waves / 256 threads");
  constexpr int BUFE = (2 * TM + 2 * TN) * BK;

  __shared__ __align__(16) u16 lds[2 * BUFE];

  const int m0 = blockIdx.x * TM;
  const int n0 = blockIdx.y * TN;

  const int tid  = threadIdx.x;
  const int w    = tid >> 6;
  const int lane = tid & 63;
  const int lr   = lane & 15;
  const int lg   = lane >> 4;
  const int wm   = w / WN;
  const int wn   = w % WN;

  const int rrA = tid >> 2;     // 0..63
  const int chA = tid & 3;      // 16B chunk

  short8 ra[2], rb[2];

  f32x4 acc[FM][FN];
  #pragma unroll
  for (int i = 0; i < FM; ++i)
    #pragma unroll
    for (int j = 0; j < FN; ++j)
      acc[i][j] = (f32x4){0.f, 0.f, 0.f, 0.f};

  auto stage_load = [&](int k0){
    int gm = m0 + rrA;
    ra[0] = *reinterpret_cast<const short8*>(Ahi + (size_t)gm * K + k0 + chA * 8);
    ra[1] = *reinterpret_cast<const short8*>(Alo + (size_t)gm * K + k0 + chA * 8);
    int gn = n0 + rrA; if (gn > N - 1) gn = N - 1;
    rb[0] = *reinterpret_cast<const short8*>(Bhi + (size_t)gn * K + k0 + chA * 8);
    rb[1] = *reinterpret_cast<const short8*>(Blo + (size_t)gn * K + k0 + chA * 8);
  };
  auto stage_store = [&](int buf){
    u16* As_hi = lds + buf * BUFE;
    u16* As_lo = As_hi + TM * BK;
    u16* Bs_hi = As_hi + 2 * TM * BK;
    u16* Bs_lo = As_hi + 2 * TM * BK + TN * BK;
    int row = rrA;
    int sw  = (chA ^ ((row >> 1) & 3)) << 3;
    *reinterpret_cast<short8*>(As_hi + row * BK + sw) = ra[0];
    *reinterpret_cast<short8*>(As_lo + row * BK + sw) = ra[1];
    *reinterpret_cast<short8*>(Bs_hi + row * BK + sw) = rb[0];
    *reinterpret_cast<short8*>(Bs_lo + row * BK + sw) = rb[1];
  };

  const int NT = K / BK;
  stage_load(0);
  stage_store(0);
  __syncthreads();

  int cur = 0;
  for (int t = 0; t < NT; ++t){
    const bool have_next = (t + 1 < NT);
    if (have_next) stage_load((t + 1) * BK);

    u16* As_hi = lds + cur * BUFE;
    u16* As_lo = As_hi + TM * BK;
    u16* Bs_hi = As_hi + 2 * TM * BK;
    u16* Bs_lo = As_hi + 2 * TM * BK + TN * BK;

    short8 ah[FM], al[FM], bh[FN], bl[FN];
    #pragma unroll
    for (int i = 0; i < FM; ++i){
      int row = wm * FM * 16 + i * 16 + lr;
      int off = row * BK + ((lg ^ ((row >> 1) & 3)) << 3);
      ah[i] = *reinterpret_cast<short8*>(As_hi + off);
      al[i] = *reinterpret_cast<short8*>(As_lo + off);
    }
    #pragma unroll
    for (int j = 0; j < FN; ++j){
      int row = wn * FN * 16 + j * 16 + lr;
      int off = row * BK + ((lg ^ ((row >> 1) & 3)) << 3);
      bh[j] = *reinterpret_cast<short8*>(Bs_hi + off);
      bl[j] = *reinterpret_cast<short8*>(Bs_lo + off);
    }
    #pragma unroll
    for (int i = 0; i < FM; ++i)
      #pragma unroll
      for (int j = 0; j < FN; ++j){
        acc[i][j] = __builtin_amdgcn_mfma_f32_16x16x32_bf16(ah[i], bh[j], acc[i][j], 0, 0, 0);
        acc[i][j] = __builtin_amdgcn_mfma_f32_16x16x32_bf16(ah[i], bl[j], acc[i][j], 0, 0, 0);
        acc[i][j] = __builtin_amdgcn_mfma_f32_16x16x32_bf16(al[i], bh[j], acc[i][j], 0, 0, 0);
      }

    if (have_next){
      __builtin_amdgcn_sched_barrier(0);
      stage_store(cur ^ 1);
      __syncthreads();
    }
    cur ^= 1;
  }

  #pragma unroll
  for (int i = 0; i < FM; ++i){
    int rbase = m0 + wm * FM * 16 + i * 16 + lg * 4;
    #pragma unroll
    for (int j = 0; j < FN; ++j){
      int gcol = n0 + wn * FN * 16 + j * 16 + lr;
      if (gcol < N){
        float cb = colBias ? colBias[gcol] : 0.f;
        #pragma unroll
        for (int r = 0; r < 4; ++r){
          int grow = rbase + r;
          float v = acc[i][j][r] + cb;
          size_t idx = (size_t)grow * N + gcol;
          if (Cf) Cf[idx] = v;
          if constexpr (OUT16 == 1){
            u16 hs = f2bf(v);
            Chi[idx] = hs;
            Clo[idx] = f2bf(v - bf2f(hs));
          } else if constexpr (OUT16 == 2){
            _Float16 h = (_Float16)v;
            Chi[idx] = __builtin_bit_cast(u16, h);
            Clo[idx] = f2h_bits(v - (float)h);
          }
        }
      }
    }
  }
}

// ---------- BIG GEMM: LDS-free, barrier-free direct-fragment, PINNED ledger ----------
// out = alpha*(A·B^T + rowAdd). A = Y fp16 [512][2048] (L2-resident), B = fp32
// templates (HBM stream) loaded directly into per-lane MFMA fragments:
//   B frag j: two f32x4 at B[n0+wn*64+j*16+lr][t*32+lg*8 (+4)] — the 64 lanes'
//   (lr,lg) pairs tile 16 rows x full 128B line across the instr pair.
// Convert after load (16 cvt_pkrtz/wave-iter). No LDS, no barriers.
// 2-deep STATIC register sets (aE/bE, aO/bO) pinned by asm WAIT_VM:
//   each iter consumes one set, reissues it for t+2, then WAIT_VM(10)
//   guarantees the other set (issued 1 iter ago) has landed. sched_barrier(0)
//   after every wait (rule #18) + "memory"-clobber keeps order exact.
// ~140 VGPR under launch_bounds(256,3) cap 168 -> 12 independent waves/CU;
// each wave's load stall is hidden by the other 2 waves on its SIMD.
__global__ __launch_bounds__(256, 3)
void gemm_big(const u16* __restrict__ Ah,      // fp16 bits [512][2048]
              const float* __restrict__ Bf,    // [50000][2048]
              float* __restrict__ C,
              const float* __restrict__ rowAdd, float alpha)
{
  constexpr int TM = 64, TN = 128, BK = 32;
  constexpr int K = FP_, NN = TT_;
  constexpr int NT = K / BK;                 // 64

  // bijective XCD grouping: xcd<7 own 49 N-strips, xcd=7 owns 48 (391 total).
  int id  = blockIdx.x;
  int xcd = id & 7;
  int g   = id >> 3;
  int mt  = g & 7;            // 8 M-tiles of 64
  int s   = g >> 3;           // 0..48
  int strips = (xcd < 7) ? 49 : 48;
  if (s >= strips) return;
  int nt = ((xcd < 7) ? xcd * 49 : 343) + s;   // 0..390
  const int m0 = mt * TM;
  const int n0 = nt * TN;

  const int tid  = threadIdx.x;
  const int w    = tid >> 6;        // 0..3
  const int lane = tid & 63;
  const int lr   = lane & 15;
  const int lg   = lane >> 4;
  const int wm   = w >> 1;          // 0..1  (32-row band of A)
  const int wn   = w & 1;           // 0..1  (64-col band of B)

  // per-lane fragment base pointers (fixed rows; k advances BK per step)
  const u16* ap0 = Ah + (size_t)(m0 + wm * 32 +  0 + lr) * K + lg * 8;
  const u16* ap1 = Ah + (size_t)(m0 + wm * 32 + 16 + lr) * K + lg * 8;
  const float* bp[4];
  #pragma unroll
  for (int j = 0; j < 4; ++j){
    int r = n0 + wn * 64 + j * 16 + lr;
    if (r > NN - 1) r = NN - 1;     // tail clamp; OOB cols masked at epilogue
    bp[j] = Bf + (size_t)r * K + lg * 8;
  }

  f32x4 acc[2][4];
  #pragma unroll
  for (int i = 0; i < 2; ++i)
    #pragma unroll
    for (int j = 0; j < 4; ++j)
      acc[i][j] = (f32x4){0.f, 0.f, 0.f, 0.f};

  // static 2-deep register sets (names keep them live & distinct)
  short8 aE0, aE1, aO0, aO1;
  f32x4  bE[4][2], bO[4][2];

  auto toh = [](const f32x4& lo, const f32x4& hi) -> f16x8 {
    u32x4 u;
    u[0] = pkrtz_u32(lo[0], lo[1]);
    u[1] = pkrtz_u32(lo[2], lo[3]);
    u[2] = pkrtz_u32(hi[0], hi[1]);
    u[3] = pkrtz_u32(hi[2], hi[3]);
    return __builtin_bit_cast(f16x8, u);
  };

#define LOAD_SET(t, a0, a1, bb)                                              \
  a0 = *reinterpret_cast<const short8*>(ap0 + (t) * BK);                     \
  a1 = *reinterpret_cast<const short8*>(ap1 + (t) * BK);                     \
  _Pragma("unroll")                                                          \
  for (int j = 0; j < 4; ++j){                                               \
    bb[j][0] = *reinterpret_cast<const f32x4*>(bp[j] + (t) * BK);            \
    bb[j][1] = *reinterpret_cast<const f32x4*>(bp[j] + (t) * BK + 4);        \
  }

#define STEP(a0, a1, bb)                                                     \
  {                                                                          \
    f16x8 bh0 = toh(bb[0][0], bb[0][1]);                                     \
    f16x8 bh1 = toh(bb[1][0], bb[1][1]);                                     \
    f16x8 bh2 = toh(bb[2][0], bb[2][1]);                                     \
    f16x8 bh3 = toh(bb[3][0], bb[3][1]);                                     \
    f16x8 ah0 = __builtin_bit_cast(f16x8, a0);                               \
    f16x8 ah1 = __builtin_bit_cast(f16x8, a1);                               \
    acc[0][0] = __builtin_amdgcn_mfma_f32_16x16x32_f16(ah0, bh0, acc[0][0], 0, 0, 0); \
    acc[0][1] = __builtin_amdgcn_mfma_f32_16x16x32_f16(ah0, bh1, acc[0][1], 0, 0, 0); \
    acc[0][2] = __builtin_amdgcn_mfma_f32_16x16x32_f16(ah0, bh2, acc[0][2], 0, 0, 0); \
    acc[0][3] = __builtin_amdgcn_mfma_f32_16x16x32_f16(ah0, bh3, acc[0][3], 0, 0, 0); \
    acc[1][0] = __builtin_amdgcn_mfma_f32_16x16x32_f16(ah1, bh0, acc[1][0], 0, 0, 0); \
    acc[1][1] = __builtin_amdgcn_mfma_f32_16x16x32_f16(ah1, bh1, acc[1][1], 0, 0, 0); \
    acc[1][2] = __builtin_amdgcn_mfma_f32_16x16x32_f16(ah1, bh2, acc[1][2], 0, 0, 0); \
    acc[1][3] = __builtin_amdgcn_mfma_f32_16x16x32_f16(ah1, bh3, acc[1][3], 0, 0, 0); \
  }

  // ---- prologue: two sets in flight; wait set0 ----
  LOAD_SET(0, aE0, aE1, bE); SCH;
  LOAD_SET(1, aO0, aO1, bO); SCH;
  WAIT_VM(10); SCH;                 // set0 ready (set1's 10 still in flight)

  // ---- main loop: consume set, reissue it t+2 ahead, wait the other set ----
  for (int t = 0; t < NT; t += 2){
    STEP(aE0, aE1, bE);                          // consume t
    if (t + 2 < NT){
      LOAD_SET(t + 2, aE0, aE1, bE); SCH;
      WAIT_VM(10); SCH;                          // (t+1)-set landed
    } else {
      WAIT_VM(0); SCH;                           // drain last odd set
    }
    STEP(aO0, aO1, bO);                          // consume t+1
    if (t + 3 < NT){
      LOAD_SET(t + 3, aO0, aO1, bO); SCH;
      WAIT_VM(10); SCH;                          // (t+2)-set landed
    } else if (t + 2 < NT){
      WAIT_VM(0); SCH;                           // drain last even set
    }
  }

  // ---- epilogue: row=(lane>>4)*4+reg (A index), col=lane&15 (B index) ----
  #pragma unroll
  for (int i = 0; i < 2; ++i){
    int rbase = m0 + wm * 32 + i * 16 + lg * 4;
    #pragma unroll
    for (int j = 0; j < 4; ++j){
      int gcol = n0 + wn * 64 + j * 16 + lr;
      if (gcol < NN){
        #pragma unroll
        for (int r = 0; r < 4; ++r){
          int grow = rbase + r;
          float v = (acc[i][j][r] + rowAdd[grow]) * alpha;
          C[(size_t)grow * NN + gcol] = v;
        }
      }
    }
  }
#undef LOAD_SET
#undef STEP
}

extern "C" void kernel_launch(void* const* d_in, const int* in_sizes, int n_in,
                              void* d_out, int out_size, void* d_ws, size_t ws_size,
                              hipStream_t stream){
  (void)in_sizes; (void)n_in; (void)out_size; (void)ws_size;
  const float* m    = (const float*)d_in[0];   // [512][2048]
  const float* tpl  = (const float*)d_in[1];   // [50000][2048]
  const float* Wmol = (const float*)d_in[2];   // [1024][2048]
  const float* bmol = (const float*)d_in[3];   // [1024]
  const float* Wtmp = (const float*)d_in[4];   // [1024][2048]
  const float* btmp = (const float*)d_in[5];   // [1024]
  float* out = (float*)d_out;                  // [512][50000]

  uint8_t* wp = (uint8_t*)d_ws;
  auto carve = [&](size_t bytes) -> void* {
    void* p = (void*)wp;
    wp += (bytes + 255) & ~(size_t)255;
    return p;
  };
  u16* m_hi   = (u16*)carve((size_t)BB_ * FP_ * 2);
  u16* m_lo   = (u16*)carve((size_t)BB_ * FP_ * 2);
  u16* wm_hi  = (u16*)carve((size_t)AD_ * FP_ * 2);
  u16* wm_lo  = (u16*)carve((size_t)AD_ * FP_ * 2);
  u16* wtT_hi = (u16*)carve((size_t)FP_ * AD_ * 2);
  u16* wtT_lo = (u16*)carve((size_t)FP_ * AD_ * 2);
  float* Xi   = (float*)carve((size_t)BB_ * AD_ * 4);
  u16* Xi_hi  = (u16*)carve((size_t)BB_ * AD_ * 2);
  u16* Xi_lo  = (u16*)carve((size_t)BB_ * AD_ * 2);
  u16* Y_hi   = (u16*)carve((size_t)BB_ * FP_ * 2);   // fp16 bits
  u16* Y_lo   = (u16*)carve((size_t)BB_ * FP_ * 2);   // fp16 bits (unused by big gemm)
  float* cvec = (float*)carve((size_t)BB_ * 4);

  // 1) split inputs to bf16 hi/lo (W_temp also transposed to [FP][A])
  conv_hilo_k<<<(BB_ * FP_ / 4 + 255) / 256, 256, 0, stream>>>(m, m_hi, m_lo, BB_ * FP_);
  conv_hilo_k<<<(AD_ * FP_ / 4 + 255) / 256, 256, 0, stream>>>(Wmol, wm_hi, wm_lo, AD_ * FP_);
  conv_hilo_T_k<<<dim3(FP_ / 32, AD_ / 32), dim3(32, 8), 0, stream>>>(Wtmp, wtT_hi, wtT_lo, AD_, FP_);

  // 2) Xi = m @ W_mol^T + b_mol   [512 x 1024], K=2048  (fp32 + bf16 hi/lo out)
  gemm_hilo<64, 64, 2, 2, 1><<<dim3(BB_ / 64, AD_ / 64), 256, 0, stream>>>(
      m_hi, m_lo, wm_hi, wm_lo, BB_, AD_, FP_,
      Xi, Xi_hi, Xi_lo, bmol);

  // 3) c[b] = Xi[b,:] . b_temp
  dot_rows_k<<<BB_ / 4, 256, 0, stream>>>(Xi, btmp, cvec, AD_);

  // 4) Y = Xi @ W_temp   [512 x 2048], K=1024  -> fp16 hi/lo (big gemm uses hi only)
  gemm_hilo<64, 64, 2, 2, 2><<<dim3(BB_ / 64, FP_ / 64), 256, 0, stream>>>(
      Xi_hi, Xi_lo, wtT_hi, wtT_lo, BB_, FP_, AD_,
      nullptr, Y_hi, Y_lo, nullptr);

  // 5) out = BETA * (Y @ templates^T + c)   [512 x 50000], K=2048
  //    3136 blocks = 8 XCD x 49 strip-slots x 8 M-tiles; 8 masked.
  gemm_big<<<3136, 256, 0, stream>>>(Y_hi, tpl, out, cvec, BETA_);
}

// Round 13
// 313.927 us; speedup vs baseline: 5.2312x; 3.1519x over previous
//
#include <hip/hip_runtime.h>
#include <cstdint>
#include <cstddef>

typedef __attribute__((ext_vector_type(8))) short short8;     // 8 x 16-bit (4 VGPRs)
typedef __attribute__((ext_vector_type(8))) _Float16 f16x8;   // fp16 MFMA frag
typedef __attribute__((ext_vector_type(4))) float f32x4;
typedef __attribute__((ext_vector_type(4))) unsigned short u16x4;
typedef unsigned short u16;

#define FP_  2048
#define AD_  1024
#define BB_  512
#define TT_  50000
#define BETA_ 0.125f

// ---------- fp32 -> bf16 (RNE) helpers ----------
__device__ __forceinline__ u16 f2bf(float x){
  uint32_t u = __builtin_bit_cast(uint32_t, x);
  u = (u + 0x7fffu + ((u >> 16) & 1u)) >> 16;
  return (u16)u;
}
__device__ __forceinline__ float bf2f(u16 h){
  uint32_t u = ((uint32_t)h) << 16;
  return __builtin_bit_cast(float, u);
}
__device__ __forceinline__ u16 f2h_bits(float x){
  _Float16 h = (_Float16)x;            // RNE
  return __builtin_bit_cast(u16, h);
}
__device__ __forceinline__ unsigned int pkrtz_u32(float a, float b){
  return __builtin_bit_cast(unsigned int, __builtin_amdgcn_cvt_pkrtz(a, b));
}

// ---------- async global->LDS, 16B per lane ----------
__device__ __forceinline__ void gload_lds16(const void* g, void* l){
  __builtin_amdgcn_global_load_lds((const __attribute__((address_space(1))) void*)g,
                                   (__attribute__((address_space(3))) void*)l,
                                   16, 0, 0);
}

#define SB   __builtin_amdgcn_s_barrier()
#define SCH  __builtin_amdgcn_sched_barrier(0)
#define WAIT_LGKM0 asm volatile("s_waitcnt lgkmcnt(0)" ::: "memory")
#define WAIT_VM(n) asm volatile("s_waitcnt vmcnt(" #n ")" ::: "memory")

// ---------- elementwise fp32 -> (hi,lo) bf16 ----------
__global__ void conv_hilo_k(const float* __restrict__ src, u16* __restrict__ hi,
                            u16* __restrict__ lo, int n){
  int i = (blockIdx.x * blockDim.x + threadIdx.x) * 4;
  if (i >= n) return;
  f32x4 v = *reinterpret_cast<const f32x4*>(src + i);
  u16x4 h, l;
  #pragma unroll
  for (int e = 0; e < 4; ++e){
    float x = v[e];
    u16 hs = f2bf(x);
    h[e] = hs;
    l[e] = f2bf(x - bf2f(hs));
  }
  *reinterpret_cast<u16x4*>(hi + i) = h;
  *reinterpret_cast<u16x4*>(lo + i) = l;
}

// ---------- W[R][C] -> out[C][R] with hi/lo split (LDS tile transpose) ----------
__global__ void conv_hilo_T_k(const float* __restrict__ W, u16* __restrict__ hiT,
                              u16* __restrict__ loT, int R, int C){
  __shared__ float tile[32][33];
  int c0 = blockIdx.x * 32;
  int r0 = blockIdx.y * 32;
  int tx = threadIdx.x;   // 0..31
  int ty = threadIdx.y;   // 0..7
  #pragma unroll
  for (int i = 0; i < 32; i += 8)
    tile[ty + i][tx] = W[(size_t)(r0 + ty + i) * C + c0 + tx];
  __syncthreads();
  #pragma unroll
  for (int i = 0; i < 32; i += 8){
    float x = tile[tx][ty + i];              // = W[r0+tx][c0+ty+i]
    u16 hs = f2bf(x);
    size_t o = (size_t)(c0 + ty + i) * R + r0 + tx;   // out[f][a]
    hiT[o] = hs;
    loT[o] = f2bf(x - bf2f(hs));
  }
}

// ---------- c[b] = dot(Xi[b,:], b_temp) : one wave per row ----------
__global__ void dot_rows_k(const float* __restrict__ Xi, const float* __restrict__ bt,
                           float* __restrict__ c, int K){
  int row  = blockIdx.x * 4 + (threadIdx.x >> 6);
  int lane = threadIdx.x & 63;
  float s = 0.f;
  for (int a = lane; a < K; a += 64) s += Xi[(size_t)row * K + a] * bt[a];
  #pragma unroll
  for (int off = 32; off; off >>= 1) s += __shfl_down(s, off);
  if (lane == 0) c[row] = s;
}

// ---------- split-bf16 small GEMM: C = A·B^T + colBias (3-term hi/lo) ----------
// OUT16: 0=none, 1=bf16 hi/lo pair, 2=fp16 hi/lo pair
template<int TM, int TN, int FM, int FN, int OUT16>
__global__ __launch_bounds__(256, 2)
void gemm_hilo(const u16* __restrict__ Ahi, const u16* __restrict__ Alo,
               const u16* __restrict__ Bhi, const u16* __restrict__ Blo,
               int M, int N, int K,
               float* __restrict__ Cf, u16* __restrict__ Chi, u16* __restrict__ Clo,
               const float* __restrict__ colBias)
{
  constexpr int BK = 32;
  constexpr int WM = TM / (16 * FM);
  constexpr int WN = TN / (16 * FN);
  static_assert(WM * WN == 4, "4 waves / 256 threads");
  constexpr int BUFE = (2 * TM + 2 * TN) * BK;

  __shared__ __align__(16) u16 lds[2 * BUFE];

  const int m0 = blockIdx.x * TM;
  const int n0 = blockIdx.y * TN;

  const int tid  = threadIdx.x;
  const int w    = tid >> 6;
  const int lane = tid & 63;
  const int lr   = lane & 15;
  const int lg   = lane >> 4;
  const int wm   = w / WN;
  const int wn   = w % WN;

  const int rrA = tid >> 2;     // 0..63
  const int chA = tid & 3;      // 16B chunk

  short8 ra[2], rb[2];

  f32x4 acc[FM][FN];
  #pragma unroll
  for (int i = 0; i < FM; ++i)
    #pragma unroll
    for (int j = 0; j < FN; ++j)
      acc[i][j] = (f32x4){0.f, 0.f, 0.f, 0.f};

  auto stage_load = [&](int k0){
    int gm = m0 + rrA;
    ra[0] = *reinterpret_cast<const short8*>(Ahi + (size_t)gm * K + k0 + chA * 8);
    ra[1] = *reinterpret_cast<const short8*>(Alo + (size_t)gm * K + k0 + chA * 8);
    int gn = n0 + rrA; if (gn > N - 1) gn = N - 1;
    rb[0] = *reinterpret_cast<const short8*>(Bhi + (size_t)gn * K + k0 + chA * 8);
    rb[1] = *reinterpret_cast<const short8*>(Blo + (size_t)gn * K + k0 + chA * 8);
  };
  auto stage_store = [&](int buf){
    u16* As_hi = lds + buf * BUFE;
    u16* As_lo = As_hi + TM * BK;
    u16* Bs_hi = As_hi + 2 * TM * BK;
    u16* Bs_lo = As_hi + 2 * TM * BK + TN * BK;
    int row = rrA;
    int sw  = (chA ^ ((row >> 1) & 3)) << 3;
    *reinterpret_cast<short8*>(As_hi + row * BK + sw) = ra[0];
    *reinterpret_cast<short8*>(As_lo + row * BK + sw) = ra[1];
    *reinterpret_cast<short8*>(Bs_hi + row * BK + sw) = rb[0];
    *reinterpret_cast<short8*>(Bs_lo + row * BK + sw) = rb[1];
  };

  const int NT = K / BK;
  stage_load(0);
  stage_store(0);
  __syncthreads();

  int cur = 0;
  for (int t = 0; t < NT; ++t){
    const bool have_next = (t + 1 < NT);
    if (have_next) stage_load((t + 1) * BK);

    u16* As_hi = lds + cur * BUFE;
    u16* As_lo = As_hi + TM * BK;
    u16* Bs_hi = As_hi + 2 * TM * BK;
    u16* Bs_lo = As_hi + 2 * TM * BK + TN * BK;

    short8 ah[FM], al[FM], bh[FN], bl[FN];
    #pragma unroll
    for (int i = 0; i < FM; ++i){
      int row = wm * FM * 16 + i * 16 + lr;
      int off = row * BK + ((lg ^ ((row >> 1) & 3)) << 3);
      ah[i] = *reinterpret_cast<short8*>(As_hi + off);
      al[i] = *reinterpret_cast<short8*>(As_lo + off);
    }
    #pragma unroll
    for (int j = 0; j < FN; ++j){
      int row = wn * FN * 16 + j * 16 + lr;
      int off = row * BK + ((lg ^ ((row >> 1) & 3)) << 3);
      bh[j] = *reinterpret_cast<short8*>(Bs_hi + off);
      bl[j] = *reinterpret_cast<short8*>(Bs_lo + off);
    }
    #pragma unroll
    for (int i = 0; i < FM; ++i)
      #pragma unroll
      for (int j = 0; j < FN; ++j){
        acc[i][j] = __builtin_amdgcn_mfma_f32_16x16x32_bf16(ah[i], bh[j], acc[i][j], 0, 0, 0);
        acc[i][j] = __builtin_amdgcn_mfma_f32_16x16x32_bf16(ah[i], bl[j], acc[i][j], 0, 0, 0);
        acc[i][j] = __builtin_amdgcn_mfma_f32_16x16x32_bf16(al[i], bh[j], acc[i][j], 0, 0, 0);
      }

    if (have_next){
      __builtin_amdgcn_sched_barrier(0);
      stage_store(cur ^ 1);
      __syncthreads();
    }
    cur ^= 1;
  }

  #pragma unroll
  for (int i = 0; i < FM; ++i){
    int rbase = m0 + wm * FM * 16 + i * 16 + lg * 4;
    #pragma unroll
    for (int j = 0; j < FN; ++j){
      int gcol = n0 + wn * FN * 16 + j * 16 + lr;
      if (gcol < N){
        float cb = colBias ? colBias[gcol] : 0.f;
        #pragma unroll
        for (int r = 0; r < 4; ++r){
          int grow = rbase + r;
          float v = acc[i][j][r] + cb;
          size_t idx = (size_t)grow * N + gcol;
          if (Cf) Cf[idx] = v;
          if constexpr (OUT16 == 1){
            u16 hs = f2bf(v);
            Chi[idx] = hs;
            Clo[idx] = f2bf(v - bf2f(hs));
          } else if constexpr (OUT16 == 2){
            _Float16 h = (_Float16)v;
            Chi[idx] = __builtin_bit_cast(u16, h);
            Clo[idx] = f2h_bits(v - (float)h);
          }
        }
      }
    }
  }
}

// ---------- BIG GEMM, BK=64 (two R6-half-tiles per barrier) ----------
// out = alpha*(A·B^T + rowAdd); A = Y fp16 [512][2048] (L2-resident),
// B = fp32 templates -> fp16 (pkrtz) in staging (HBM stream).
// TM=64 x TN=128; compute iter u covers k-halves {2u, 2u+1} (BK_half=32).
// 4 half-buffers of 12KB (A 4KB + B 8KB, R6 layout/swizzle) = 48KB
// -> 3 blocks/CU. 4 static B-reg half-sets rb0..rb3 (slot = half%4),
// 2-iter unroll for static indexing (rule #20).
// Per-iter issues (pinned): [A(2u+2):1, A(2u+3):1, B(2u+4):4, B(2u+5):4].
// Invariant entering u: Q=[B(2u+2):4, B(2u+3):4]=8.
//   post-MFMA: vmcnt(14)->publish B(2u+2); vmcnt(10)->publish B(2u+3);
//   vmcnt(8)->A landed; lgkm0; ONE s_barrier per 64-k iter.
// Tail u=30: 6/2/0. u=31: compute only.
__global__ __launch_bounds__(256, 3)
void gemm_big(const u16* __restrict__ Ah,      // fp16 bits [512][2048]
              const float* __restrict__ Bf,    // [50000][2048]
              float* __restrict__ C,
              const float* __restrict__ rowAdd, float alpha)
{
  constexpr int TM = 64, TN = 128, BKH = 32;
  constexpr int K = FP_, NN = TT_;
  constexpr int NU = K / 64;                 // 32 compute iters
  constexpr int SLOT_A = TM * BKH;           // 2048 u16 = 4KB
  constexpr int HBUF   = SLOT_A + TN * BKH;  // 6144 u16 = 12KB

  __shared__ __align__(16) u16 lds[4 * HBUF];   // 48KB

  // bijective XCD grouping: xcd<7 own 49 N-strips, xcd=7 owns 48 (391 total).
  int id  = blockIdx.x;
  int xcd = id & 7;
  int g   = id >> 3;
  int mt  = g & 7;            // 8 M-tiles of 64
  int s   = g >> 3;           // 0..48
  int strips = (xcd < 7) ? 49 : 48;
  if (s >= strips) return;
  int nt = ((xcd < 7) ? xcd * 49 : 343) + s;   // 0..390
  const int m0 = mt * TM;
  const int n0 = nt * TN;

  const int tid  = threadIdx.x;
  const int w    = tid >> 6;        // 0..3
  const int lane = tid & 63;
  const int lr   = lane & 15;
  const int lg   = lane >> 4;
  const int wm   = w >> 1;          // 0..1  (32-row band)
  const int wn   = w & 1;           // 0..1  (64-col band)

  const int rowB = tid >> 3;        // 0..31
  const int c4   = tid & 7;         // f32x4 chunk in a 32-float row

  // ---- per-half staging helpers (R6 mechanics, h = k-half index) ----
  auto issueA = [&](int h, u16* sp){           // 1 vmcnt entry per wave
    int rloc = lane >> 2;                      // 0..15
    int cc   = lane & 3;
    int row  = w * 16 + rloc;
    int sc   = cc ^ ((row >> 1) & 3);          // inverse swizzle on source
    const u16* gh = Ah + (size_t)(m0 + row) * K + h * BKH + sc * 8;
    gload_lds16(gh, sp + w * 16 * BKH);        // wave-uniform dest + lane*16B
  };
  auto issueB = [&](int h, f32x4 (&rb)[4]){    // 4 vmcnt entries per wave
    #pragma unroll
    for (int p = 0; p < 4; ++p){
      int gn = n0 + rowB + p * 32; if (gn > NN - 1) gn = NN - 1;
      rb[p] = *reinterpret_cast<const f32x4*>(Bf + (size_t)gn * K + h * BKH + c4 * 4);
    }
  };
  auto writeB = [&](u16* sp, f32x4 (&rb)[4]){
    u16* bb = sp + SLOT_A;
    #pragma unroll
    for (int p = 0; p < 4; ++p){
      int row = rowB + p * 32;
      uint2 hv;
      hv.x = pkrtz_u32(rb[p][0], rb[p][1]);
      hv.y = pkrtz_u32(rb[p][2], rb[p][3]);
      int q   = c4 >> 1;
      int off = row * BKH + ((q ^ ((row >> 1) & 3)) << 3) + (c4 & 1) * 4;
      *reinterpret_cast<uint2*>(bb + off) = hv;
    }
  };

  f32x4 acc[2][4];
  #pragma unroll
  for (int i = 0; i < 2; ++i)
    #pragma unroll
    for (int j = 0; j < 4; ++j)
      acc[i][j] = (f32x4){0.f, 0.f, 0.f, 0.f};

  f32x4 rb0[4], rb1[4], rb2[4], rb3[4];   // B half-sets, slot = half%4

  // ---- prologue: A halves 0-3 (DMA), B halves 0-3 (regs); publish 0,1 ----
  issueA(0, lds);
  issueA(1, lds + HBUF);
  issueA(2, lds + 2 * HBUF);
  issueA(3, lds + 3 * HBUF);          // 4
  SCH;
  issueB(0, rb0); issueB(1, rb1);
  issueB(2, rb2); issueB(3, rb3);     // +16 -> Q=20
  SCH;
  WAIT_VM(12);                        // A0-3 + B0 retired
  writeB(lds, rb0);
  WAIT_VM(8);                         // B1 retired
  writeB(lds + HBUF, rb1);
  WAIT_LGKM0;
  SB; SCH;                            // Q = [B2:4, B3:4] = 8

  // ---- body: compute halves {2u,2u+1}; issue A(2u+2,2u+3), B(2u+4,2u+5);
  //      publish B(2u+2), B(2u+3) ----
  auto body = [&](int u, f32x4 (&pubX)[4], f32x4 (&pubY)[4],
                         f32x4 (&filX)[4], f32x4 (&filY)[4]){
    u16* bc0 = lds + (size_t)((2 * u)     & 3) * HBUF;
    u16* bc1 = lds + (size_t)((2 * u + 1) & 3) * HBUF;
    u16* bw0 = lds + (size_t)((2 * u + 2) & 3) * HBUF;
    u16* bw1 = lds + (size_t)((2 * u + 3) & 3) * HBUF;

    if (u + 1 < NU){ issueA(2 * u + 2, bw0); issueA(2 * u + 3, bw1); }
    SCH;
    if (u + 2 < NU){ issueB(2 * u + 4, filX); issueB(2 * u + 5, filY); }
    SCH;

    f16x8 a0[2], a1[2], b0[4], b1[4];
    #pragma unroll
    for (int i = 0; i < 2; ++i){
      int row = wm * 32 + i * 16 + lr;
      int off = row * BKH + ((lg ^ ((row >> 1) & 3)) << 3);
      a0[i] = __builtin_bit_cast(f16x8, *reinterpret_cast<short8*>(bc0 + off));
      a1[i] = __builtin_bit_cast(f16x8, *reinterpret_cast<short8*>(bc1 + off));
    }
    #pragma unroll
    for (int j = 0; j < 4; ++j){
      int row = wn * 64 + j * 16 + lr;
      int off = row * BKH + ((lg ^ ((row >> 1) & 3)) << 3);
      b0[j] = __builtin_bit_cast(f16x8, *reinterpret_cast<short8*>(bc0 + SLOT_A + off));
      b1[j] = __builtin_bit_cast(f16x8, *reinterpret_cast<short8*>(bc1 + SLOT_A + off));
    }
    WAIT_LGKM0; SCH;
    #pragma unroll
    for (int i = 0; i < 2; ++i)
      #pragma unroll
      for (int j = 0; j < 4; ++j){
        acc[i][j] = __builtin_amdgcn_mfma_f32_16x16x32_f16(a0[i], b0[j], acc[i][j], 0, 0, 0);
        acc[i][j] = __builtin_amdgcn_mfma_f32_16x16x32_f16(a1[i], b1[j], acc[i][j], 0, 0, 0);
      }
    SCH;

    if (u + 1 < NU){
      if (u + 2 < NU) { WAIT_VM(14); } else { WAIT_VM(6); }   // B(2u+2) retired
      writeB(bw0, pubX);
      if (u + 2 < NU) { WAIT_VM(10); } else { WAIT_VM(2); }   // B(2u+3) retired
      writeB(bw1, pubY);
      if (u + 2 < NU) { WAIT_VM(8); }  else { WAIT_VM(0); }   // A(2u+2,3) landed
      WAIT_LGKM0;
      SB; SCH;
    }
  };

  // slot rotation: even u publishes rb2,rb3 / fills rb0,rb1; odd u swaps.
  for (int uu = 0; uu < NU; uu += 2){
    body(uu,     rb2, rb3, rb0, rb1);
    body(uu + 1, rb0, rb1, rb2, rb3);
  }

  // ---- epilogue: row=(lane>>4)*4+reg (A index), col=lane&15 (B index) ----
  #pragma unroll
  for (int i = 0; i < 2; ++i){
    int rbase = m0 + wm * 32 + i * 16 + lg * 4;
    #pragma unroll
    for (int j = 0; j < 4; ++j){
      int gcol = n0 + wn * 64 + j * 16 + lr;
      if (gcol < NN){
        #pragma unroll
        for (int r = 0; r < 4; ++r){
          int grow = rbase + r;
          float v = (acc[i][j][r] + rowAdd[grow]) * alpha;
          C[(size_t)grow * NN + gcol] = v;
        }
      }
    }
  }
}

extern "C" void kernel_launch(void* const* d_in, const int* in_sizes, int n_in,
                              void* d_out, int out_size, void* d_ws, size_t ws_size,
                              hipStream_t stream){
  (void)in_sizes; (void)n_in; (void)out_size; (void)ws_size;
  const float* m    = (const float*)d_in[0];   // [512][2048]
  const float* tpl  = (const float*)d_in[1];   // [50000][2048]
  const float* Wmol = (const float*)d_in[2];   // [1024][2048]
  const float* bmol = (const float*)d_in[3];   // [1024]
  const float* Wtmp = (const float*)d_in[4];   // [1024][2048]
  const float* btmp = (const float*)d_in[5];   // [1024]
  float* out = (float*)d_out;                  // [512][50000]

  uint8_t* wp = (uint8_t*)d_ws;
  auto carve = [&](size_t bytes) -> void* {
    void* p = (void*)wp;
    wp += (bytes + 255) & ~(size_t)255;
    return p;
  };
  u16* m_hi   = (u16*)carve((size_t)BB_ * FP_ * 2);
  u16* m_lo   = (u16*)carve((size_t)BB_ * FP_ * 2);
  u16* wm_hi  = (u16*)carve((size_t)AD_ * FP_ * 2);
  u16* wm_lo  = (u16*)carve((size_t)AD_ * FP_ * 2);
  u16* wtT_hi = (u16*)carve((size_t)FP_ * AD_ * 2);
  u16* wtT_lo = (u16*)carve((size_t)FP_ * AD_ * 2);
  float* Xi   = (float*)carve((size_t)BB_ * AD_ * 4);
  u16* Xi_hi  = (u16*)carve((size_t)BB_ * AD_ * 2);
  u16* Xi_lo  = (u16*)carve((size_t)BB_ * AD_ * 2);
  u16* Y_hi   = (u16*)carve((size_t)BB_ * FP_ * 2);   // fp16 bits
  u16* Y_lo   = (u16*)carve((size_t)BB_ * FP_ * 2);   // fp16 bits (unused by big gemm)
  float* cvec = (float*)carve((size_t)BB_ * 4);

  // 1) split inputs to bf16 hi/lo (W_temp also transposed to [FP][A])
  conv_hilo_k<<<(BB_ * FP_ / 4 + 255) / 256, 256, 0, stream>>>(m, m_hi, m_lo, BB_ * FP_);
  conv_hilo_k<<<(AD_ * FP_ / 4 + 255) / 256, 256, 0, stream>>>(Wmol, wm_hi, wm_lo, AD_ * FP_);
  conv_hilo_T_k<<<dim3(FP_ / 32, AD_ / 32), dim3(32, 8), 0, stream>>>(Wtmp, wtT_hi, wtT_lo, AD_, FP_);

  // 2) Xi = m @ W_mol^T + b_mol   [512 x 1024], K=2048  (fp32 + bf16 hi/lo out)
  gemm_hilo<64, 64, 2, 2, 1><<<dim3(BB_ / 64, AD_ / 64), 256, 0, stream>>>(
      m_hi, m_lo, wm_hi, wm_lo, BB_, AD_, FP_,
      Xi, Xi_hi, Xi_lo, bmol);

  // 3) c[b] = Xi[b,:] . b_temp
  dot_rows_k<<<BB_ / 4, 256, 0, stream>>>(Xi, btmp, cvec, AD_);

  // 4) Y = Xi @ W_temp   [512 x 2048], K=1024  -> fp16 hi/lo (big gemm uses hi only)
  gemm_hilo<64, 64, 2, 2, 2><<<dim3(BB_ / 64, FP_ / 64), 256, 0, stream>>>(
      Xi_hi, Xi_lo, wtT_hi, wtT_lo, BB_, FP_, AD_,
      nullptr, Y_hi, Y_lo, nullptr);

  // 5) out = BETA * (Y @ templates^T + c)   [512 x 50000], K=2048
  //    3136 blocks = 8 XCD x 49 strip-slots x 8 M-tiles; 8 masked. 3 blocks/CU.
  gemm_big<<<3136, 256, 0, stream>>>(Y_hi, tpl, out, cvec, BETA_);
}

// Round 14
// 256.916 us; speedup vs baseline: 6.3921x; 1.2219x over previous
//
#include <hip/hip_runtime.h>
#include <cstdint>
#include <cstddef>

typedef __attribute__((ext_vector_type(8))) short short8;     // 8 x 16-bit (4 VGPRs)
typedef __attribute__((ext_vector_type(8))) _Float16 f16x8;   // fp16 MFMA frag
typedef __attribute__((ext_vector_type(4))) float f32x4;
typedef __attribute__((ext_vector_type(4))) unsigned short u16x4;
typedef unsigned short u16;

#define FP_  2048
#define AD_  1024
#define BB_  512
#define TT_  50000
#define BETA_ 0.125f

// ---------- fp32 -> bf16 (RNE) helpers ----------
__device__ __forceinline__ u16 f2bf(float x){
  uint32_t u = __builtin_bit_cast(uint32_t, x);
  u = (u + 0x7fffu + ((u >> 16) & 1u)) >> 16;
  return (u16)u;
}
__device__ __forceinline__ float bf2f(u16 h){
  uint32_t u = ((uint32_t)h) << 16;
  return __builtin_bit_cast(float, u);
}
__device__ __forceinline__ u16 f2h_bits(float x){
  _Float16 h = (_Float16)x;            // RNE
  return __builtin_bit_cast(u16, h);
}
__device__ __forceinline__ unsigned int pkrtz_u32(float a, float b){
  return __builtin_bit_cast(unsigned int, __builtin_amdgcn_cvt_pkrtz(a, b));
}

// ---------- async global->LDS, 16B per lane ----------
__device__ __forceinline__ void gload_lds16(const void* g, void* l){
  __builtin_amdgcn_global_load_lds((const __attribute__((address_space(1))) void*)g,
                                   (__attribute__((address_space(3))) void*)l,
                                   16, 0, 0);
}

#define SB   __builtin_amdgcn_s_barrier()
#define SCH  __builtin_amdgcn_sched_barrier(0)
#define WAIT_LGKM0 asm volatile("s_waitcnt lgkmcnt(0)" ::: "memory")
#define WAIT_VM(n) asm volatile("s_waitcnt vmcnt(" #n ")" ::: "memory")

// ---------- elementwise fp32 -> (hi,lo) bf16 ----------
__global__ void conv_hilo_k(const float* __restrict__ src, u16* __restrict__ hi,
                            u16* __restrict__ lo, int n){
  int i = (blockIdx.x * blockDim.x + threadIdx.x) * 4;
  if (i >= n) return;
  f32x4 v = *reinterpret_cast<const f32x4*>(src + i);
  u16x4 h, l;
  #pragma unroll
  for (int e = 0; e < 4; ++e){
    float x = v[e];
    u16 hs = f2bf(x);
    h[e] = hs;
    l[e] = f2bf(x - bf2f(hs));
  }
  *reinterpret_cast<u16x4*>(hi + i) = h;
  *reinterpret_cast<u16x4*>(lo + i) = l;
}

// ---------- W[R][C] -> out[C][R] with hi/lo split (LDS tile transpose) ----------
__global__ void conv_hilo_T_k(const float* __restrict__ W, u16* __restrict__ hiT,
                              u16* __restrict__ loT, int R, int C){
  __shared__ float tile[32][33];
  int c0 = blockIdx.x * 32;
  int r0 = blockIdx.y * 32;
  int tx = threadIdx.x;   // 0..31
  int ty = threadIdx.y;   // 0..7
  #pragma unroll
  for (int i = 0; i < 32; i += 8)
    tile[ty + i][tx] = W[(size_t)(r0 + ty + i) * C + c0 + tx];
  __syncthreads();
  #pragma unroll
  for (int i = 0; i < 32; i += 8){
    float x = tile[tx][ty + i];              // = W[r0+tx][c0+ty+i]
    u16 hs = f2bf(x);
    size_t o = (size_t)(c0 + ty + i) * R + r0 + tx;   // out[f][a]
    hiT[o] = hs;
    loT[o] = f2bf(x - bf2f(hs));
  }
}

// ---------- c[b] = dot(Xi[b,:], b_temp) : one wave per row ----------
__global__ void dot_rows_k(const float* __restrict__ Xi, const float* __restrict__ bt,
                           float* __restrict__ c, int K){
  int row  = blockIdx.x * 4 + (threadIdx.x >> 6);
  int lane = threadIdx.x & 63;
  float s = 0.f;
  for (int a = lane; a < K; a += 64) s += Xi[(size_t)row * K + a] * bt[a];
  #pragma unroll
  for (int off = 32; off; off >>= 1) s += __shfl_down(s, off);
  if (lane == 0) c[row] = s;
}

// ---------- split-bf16 small GEMM: C = A·B^T + colBias (3-term hi/lo) ----------
// OUT16: 0=none, 1=bf16 hi/lo pair, 2=fp16 hi/lo pair
template<int TM, int TN, int FM, int FN, int OUT16>
__global__ __launch_bounds__(256, 2)
void gemm_hilo(const u16* __restrict__ Ahi, const u16* __restrict__ Alo,
               const u16* __restrict__ Bhi, const u16* __restrict__ Blo,
               int M, int N, int K,
               float* __restrict__ Cf, u16* __restrict__ Chi, u16* __restrict__ Clo,
               const float* __restrict__ colBias)
{
  constexpr int BK = 32;
  constexpr int WM = TM / (16 * FM);
  constexpr int WN = TN / (16 * FN);
  static_assert(WM * WN == 4, "4 waves / 256 threads");
  constexpr int BUFE = (2 * TM + 2 * TN) * BK;

  __shared__ __align__(16) u16 lds[2 * BUFE];

  const int m0 = blockIdx.x * TM;
  const int n0 = blockIdx.y * TN;

  const int tid  = threadIdx.x;
  const int w    = tid >> 6;
  const int lane = tid & 63;
  const int lr   = lane & 15;
  const int lg   = lane >> 4;
  const int wm   = w / WN;
  const int wn   = w % WN;

  const int rrA = tid >> 2;     // 0..63
  const int chA = tid & 3;      // 16B chunk

  short8 ra[2], rb[2];

  f32x4 acc[FM][FN];
  #pragma unroll
  for (int i = 0; i < FM; ++i)
    #pragma unroll
    for (int j = 0; j < FN; ++j)
      acc[i][j] = (f32x4){0.f, 0.f, 0.f, 0.f};

  auto stage_load = [&](int k0){
    int gm = m0 + rrA;
    ra[0] = *reinterpret_cast<const short8*>(Ahi + (size_t)gm * K + k0 + chA * 8);
    ra[1] = *reinterpret_cast<const short8*>(Alo + (size_t)gm * K + k0 + chA * 8);
    int gn = n0 + rrA; if (gn > N - 1) gn = N - 1;
    rb[0] = *reinterpret_cast<const short8*>(Bhi + (size_t)gn * K + k0 + chA * 8);
    rb[1] = *reinterpret_cast<const short8*>(Blo + (size_t)gn * K + k0 + chA * 8);
  };
  auto stage_store = [&](int buf){
    u16* As_hi = lds + buf * BUFE;
    u16* As_lo = As_hi + TM * BK;
    u16* Bs_hi = As_hi + 2 * TM * BK;
    u16* Bs_lo = As_hi + 2 * TM * BK + TN * BK;
    int row = rrA;
    int sw  = (chA ^ ((row >> 1) & 3)) << 3;
    *reinterpret_cast<short8*>(As_hi + row * BK + sw) = ra[0];
    *reinterpret_cast<short8*>(As_lo + row * BK + sw) = ra[1];
    *reinterpret_cast<short8*>(Bs_hi + row * BK + sw) = rb[0];
    *reinterpret_cast<short8*>(Bs_lo + row * BK + sw) = rb[1];
  };

  const int NT = K / BK;
  stage_load(0);
  stage_store(0);
  __syncthreads();

  int cur = 0;
  for (int t = 0; t < NT; ++t){
    const bool have_next = (t + 1 < NT);
    if (have_next) stage_load((t + 1) * BK);

    u16* As_hi = lds + cur * BUFE;
    u16* As_lo = As_hi + TM * BK;
    u16* Bs_hi = As_hi + 2 * TM * BK;
    u16* Bs_lo = As_hi + 2 * TM * BK + TN * BK;

    short8 ah[FM], al[FM], bh[FN], bl[FN];
    #pragma unroll
    for (int i = 0; i < FM; ++i){
      int row = wm * FM * 16 + i * 16 + lr;
      int off = row * BK + ((lg ^ ((row >> 1) & 3)) << 3);
      ah[i] = *reinterpret_cast<short8*>(As_hi + off);
      al[i] = *reinterpret_cast<short8*>(As_lo + off);
    }
    #pragma unroll
    for (int j = 0; j < FN; ++j){
      int row = wn * FN * 16 + j * 16 + lr;
      int off = row * BK + ((lg ^ ((row >> 1) & 3)) << 3);
      bh[j] = *reinterpret_cast<short8*>(Bs_hi + off);
      bl[j] = *reinterpret_cast<short8*>(Bs_lo + off);
    }
    #pragma unroll
    for (int i = 0; i < FM; ++i)
      #pragma unroll
      for (int j = 0; j < FN; ++j){
        acc[i][j] = __builtin_amdgcn_mfma_f32_16x16x32_bf16(ah[i], bh[j], acc[i][j], 0, 0, 0);
        acc[i][j] = __builtin_amdgcn_mfma_f32_16x16x32_bf16(ah[i], bl[j], acc[i][j], 0, 0, 0);
        acc[i][j] = __builtin_amdgcn_mfma_f32_16x16x32_bf16(al[i], bh[j], acc[i][j], 0, 0, 0);
      }

    if (have_next){
      __builtin_amdgcn_sched_barrier(0);
      stage_store(cur ^ 1);
      __syncthreads();
    }
    cur ^= 1;
  }

  #pragma unroll
  for (int i = 0; i < FM; ++i){
    int rbase = m0 + wm * FM * 16 + i * 16 + lg * 4;
    #pragma unroll
    for (int j = 0; j < FN; ++j){
      int gcol = n0 + wn * FN * 16 + j * 16 + lr;
      if (gcol < N){
        float cb = colBias ? colBias[gcol] : 0.f;
        #pragma unroll
        for (int r = 0; r < 4; ++r){
          int grow = rbase + r;
          float v = acc[i][j][r] + cb;
          size_t idx = (size_t)grow * N + gcol;
          if (Cf) Cf[idx] = v;
          if constexpr (OUT16 == 1){
            u16 hs = f2bf(v);
            Chi[idx] = hs;
            Clo[idx] = f2bf(v - bf2f(hs));
          } else if constexpr (OUT16 == 2){
            _Float16 h = (_Float16)v;
            Chi[idx] = __builtin_bit_cast(u16, h);
            Clo[idx] = f2h_bits(v - (float)h);
          }
        }
      }
    }
  }
}

// ---------- BIG GEMM: 256x256 8-phase counted-vmcnt template (m201 port) ----------
// out = alpha*(A·B^T + rowAdd). A = Y fp16 [512][2048] (L2-res., global_load_lds);
// B = fp32 templates, reg-staged 1.5 K-tiles ahead, pkrtz-converted, published
// into the NEXT dbuf slot during phases 2/3.
// 512 thr = 8 waves (2M x 4N), wave tile 128x64, acc 8x4 f32x4 frags.
// K-tile BK=64 as 2x [row][32fp16] sub-blocks (64B rows, R6-verified swizzle).
// LDS: 2 slots x (A 32KB + B 32KB) = 128KB -> 1 block/CU.
// Per K-tile: 4 phases {12 ds_read; stage; SB; lgkm0; setprio1; 16 MFMA;
// setprio0; SB}. Ledger (A-half=2 entries, B-half=4): invariant entering T =
// [B0(T+1):4, B1(T+1):4]=8; steady waits all vmcnt(8); tail T=30: 8/4/0.
__global__ __launch_bounds__(512, 1)
void gemm_big(const u16* __restrict__ Ah,      // fp16 bits [512][2048]
              const float* __restrict__ Bf,    // [50000][2048]
              float* __restrict__ C,
              const float* __restrict__ rowAdd, float alpha)
{
  constexpr int K = FP_, NN = TT_;
  constexpr int NT = K / 64;                  // 32 K-tiles
  constexpr int KS = 8192;                    // u16 per ksub block (256x32)
  constexpr int BOFF = 16384;                 // B region offset (u16)
  constexpr int SLOT = 32768;                 // u16 per slot (64KB)

  __shared__ __align__(16) u16 lds[2 * SLOT]; // 128KB

  // XCD-bijective: 196 N-tiles of 256; xcd<4 own 25 strips, xcd>=4 own 24.
  int id  = blockIdx.x;
  int xcd = id & 7;
  int g   = id >> 3;          // 0..49
  int mt  = g & 1;            // 2 M-tiles of 256
  int sg  = g >> 1;           // 0..24
  int strips = (xcd < 4) ? 25 : 24;
  if (sg >= strips) return;
  int nt = ((xcd < 4) ? xcd * 25 : 100 + (xcd - 4) * 24) + sg;   // 0..195
  const int m0 = mt * 256;
  const int n0 = nt * 256;

  const int tid  = threadIdx.x;     // 0..511
  const int w    = tid >> 6;        // 0..7
  const int lane = tid & 63;
  const int lr   = lane & 15;
  const int lg   = lane >> 4;
  const int wm   = w >> 2;          // 0..1 (128-row band)
  const int wn   = w & 3;           // 0..3 (64-col band)

  // ---- A: global_load_lds, 2 calls per half (ks=0,1), linear dest ----
  auto glA = [&](u16* sp_, int Tt, int h){
    int rl = lane >> 2;             // 0..15
    int cc = lane & 3;              // 16B chunk of 64B row
    int row = h * 128 + w * 16 + rl;
    #pragma unroll
    for (int ks = 0; ks < 2; ++ks){
      const u16* src = Ah + (size_t)(m0 + row) * K + Tt * 64 + ks * 32
                     + ((cc ^ ((row >> 1) & 3)) << 3);
      gload_lds16(src, sp_ + ks * KS + (size_t)(h * 128 + w * 16) * 32);
    }
  };
  // ---- B: 4 coalesced f32x4 loads per thread per half ----
  auto issueB = [&](int Tt, int h, f32x4 (&rb)[4]){
    #pragma unroll
    for (int p = 0; p < 4; ++p){
      int rl = h * 128 + p * 32 + (tid >> 4);
      int gn = n0 + rl; if (gn > NN - 1) gn = NN - 1;
      rb[p] = *reinterpret_cast<const f32x4*>(Bf + (size_t)gn * K + Tt * 64 + (tid & 15) * 4);
    }
  };
  auto publishB = [&](u16* sp_, int h, f32x4 (&rb)[4]){
    int fch = tid & 15;
    int ks  = fch >> 3;
    int c16 = (fch & 7) >> 1;
    int hf  = fch & 1;
    #pragma unroll
    for (int p = 0; p < 4; ++p){
      int row = h * 128 + p * 32 + (tid >> 4);
      uint2 hv;
      hv.x = pkrtz_u32(rb[p][0], rb[p][1]);
      hv.y = pkrtz_u32(rb[p][2], rb[p][3]);
      int phys = c16 ^ ((row >> 1) & 3);
      *reinterpret_cast<uint2*>(sp_ + BOFF + ks * KS + row * 32 + phys * 8 + hf * 4) = hv;
    }
  };

  f32x4 acc[8][4];
  #pragma unroll
  for (int i = 0; i < 8; ++i)
    #pragma unroll
    for (int j = 0; j < 4; ++j)
      acc[i][j] = (f32x4){0.f, 0.f, 0.f, 0.f};

  f32x4 rbB0[4], rbB1[4];           // B-half reg sets (static names)
  f16x8 pa[4][2], pb[2][2];         // per-phase frags (static-indexed)

#define READ_FRAGS(SP, MH, NH)                                                 \
  _Pragma("unroll")                                                            \
  for (int ii = 0; ii < 4; ++ii){                                              \
    int row_ = wm * 128 + ((MH) * 4 + ii) * 16 + lr;                           \
    _Pragma("unroll")                                                          \
    for (int ks_ = 0; ks_ < 2; ++ks_)                                          \
      pa[ii][ks_] = __builtin_bit_cast(f16x8, *reinterpret_cast<short8*>(      \
        (SP) + ks_ * KS + row_ * 32 + ((lg ^ ((row_ >> 1) & 3)) << 3)));       \
  }                                                                            \
  _Pragma("unroll")                                                            \
  for (int jj = 0; jj < 2; ++jj){                                              \
    int row_ = wn * 64 + ((NH) * 2 + jj) * 16 + lr;                            \
    _Pragma("unroll")                                                          \
    for (int ks_ = 0; ks_ < 2; ++ks_)                                          \
      pb[jj][ks_] = __builtin_bit_cast(f16x8, *reinterpret_cast<short8*>(      \
        (SP) + BOFF + ks_ * KS + row_ * 32 + ((lg ^ ((row_ >> 1) & 3)) << 3)));\
  }

#define MMA(MH, NH)                                                            \
  __builtin_amdgcn_s_setprio(1);                                               \
  _Pragma("unroll")                                                            \
  for (int ii = 0; ii < 4; ++ii)                                               \
    _Pragma("unroll")                                                          \
    for (int jj = 0; jj < 2; ++jj){                                            \
      acc[(MH)*4+ii][(NH)*2+jj] = __builtin_amdgcn_mfma_f32_16x16x32_f16(      \
          pa[ii][0], pb[jj][0], acc[(MH)*4+ii][(NH)*2+jj], 0, 0, 0);           \
      acc[(MH)*4+ii][(NH)*2+jj] = __builtin_amdgcn_mfma_f32_16x16x32_f16(      \
          pa[ii][1], pb[jj][1], acc[(MH)*4+ii][(NH)*2+jj], 0, 0, 0);           \
    }                                                                          \
  __builtin_amdgcn_s_setprio(0);

  // ---- prologue: tile0 staged+published into slot0; B(1) sets in flight ----
  glA(lds, 0, 0);  glA(lds, 0, 1);    // 4 entries
  SCH;
  issueB(0, 0, rbB0);                 // 8
  issueB(0, 1, rbB1);                 // 12
  SCH;
  WAIT_VM(4); SCH;                    // A(0) + B0(0) retired
  publishB(lds, 0, rbB0);
  WAIT_VM(0); SCH;                    // B1(0) retired
  publishB(lds, 1, rbB1);
  SCH;
  issueB(1, 0, rbB0);                 // 4
  issueB(1, 1, rbB1);                 // 8
  WAIT_LGKM0;
  SB; SCH;
  // entering T=0: outstanding [B0(1):4, B1(1):4] = 8  (invariant)

  for (int T = 0; T < NT; ++T){
    u16* sp  = lds + (size_t)(T & 1) * SLOT;
    u16* spn = lds + (size_t)((T + 1) & 1) * SLOT;
    const bool hasN  = (T + 1 < NT);
    const bool hasNN = (T + 2 < NT);

    // ---- phase 1: quadrant (0,0); stage A0(T+1) ----
    READ_FRAGS(sp, 0, 0);
    if (hasN) glA(spn, T + 1, 0);
    SB; WAIT_LGKM0; SCH;
    MMA(0, 0);
    SB;

    // ---- phase 2: quadrant (0,1); stage A1(T+1); publish B0(T+1); issue B0(T+2) ----
    READ_FRAGS(sp, 0, 1);
    if (hasN){
      glA(spn, T + 1, 1);
      SCH;
      WAIT_VM(8); SCH;                         // B0(T+1) retired
      publishB(spn, 0, rbB0);
      if (hasNN){ issueB(T + 2, 0, rbB0); SCH; }
    }
    SB; WAIT_LGKM0; SCH;
    MMA(0, 1);
    SB;

    // ---- phase 3: quadrant (1,0); publish B1(T+1); issue B1(T+2) ----
    READ_FRAGS(sp, 1, 0);
    if (hasN){
      if (hasNN) { WAIT_VM(8); } else { WAIT_VM(4); }   // B1(T+1) retired
      SCH;
      publishB(spn, 1, rbB1);
      if (hasNN){ issueB(T + 2, 1, rbB1); SCH; }
    }
    SB; WAIT_LGKM0; SCH;
    MMA(1, 0);
    SB;

    // ---- phase 4: quadrant (1,1); confirm A(T+1) landed ----
    READ_FRAGS(sp, 1, 1);
    if (hasN){
      if (hasNN) { WAIT_VM(8); } else { WAIT_VM(0); }   // A(T+1) in LDS
      SCH;
    }
    SB; WAIT_LGKM0; SCH;
    MMA(1, 1);
    SB;
  }

#undef READ_FRAGS
#undef MMA

  // ---- epilogue: row=(lane>>4)*4+reg (A idx), col=lane&15 (B idx) ----
  #pragma unroll
  for (int i = 0; i < 8; ++i){
    int rbase = m0 + wm * 128 + i * 16 + lg * 4;
    #pragma unroll
    for (int j = 0; j < 4; ++j){
      int gcol = n0 + wn * 64 + j * 16 + lr;
      if (gcol < NN){
        #pragma unroll
        for (int r = 0; r < 4; ++r){
          int grow = rbase + r;
          float v = (acc[i][j][r] + rowAdd[grow]) * alpha;
          C[(size_t)grow * NN + gcol] = v;
        }
      }
    }
  }
}

extern "C" void kernel_launch(void* const* d_in, const int* in_sizes, int n_in,
                              void* d_out, int out_size, void* d_ws, size_t ws_size,
                              hipStream_t stream){
  (void)in_sizes; (void)n_in; (void)out_size; (void)ws_size;
  const float* m    = (const float*)d_in[0];   // [512][2048]
  const float* tpl  = (const float*)d_in[1];   // [50000][2048]
  const float* Wmol = (const float*)d_in[2];   // [1024][2048]
  const float* bmol = (const float*)d_in[3];   // [1024]
  const float* Wtmp = (const float*)d_in[4];   // [1024][2048]
  const float* btmp = (const float*)d_in[5];   // [1024]
  float* out = (float*)d_out;                  // [512][50000]

  uint8_t* wp = (uint8_t*)d_ws;
  auto carve = [&](size_t bytes) -> void* {
    void* p = (void*)wp;
    wp += (bytes + 255) & ~(size_t)255;
    return p;
  };
  u16* m_hi   = (u16*)carve((size_t)BB_ * FP_ * 2);
  u16* m_lo   = (u16*)carve((size_t)BB_ * FP_ * 2);
  u16* wm_hi  = (u16*)carve((size_t)AD_ * FP_ * 2);
  u16* wm_lo  = (u16*)carve((size_t)AD_ * FP_ * 2);
  u16* wtT_hi = (u16*)carve((size_t)FP_ * AD_ * 2);
  u16* wtT_lo = (u16*)carve((size_t)FP_ * AD_ * 2);
  float* Xi   = (float*)carve((size_t)BB_ * AD_ * 4);
  u16* Xi_hi  = (u16*)carve((size_t)BB_ * AD_ * 2);
  u16* Xi_lo  = (u16*)carve((size_t)BB_ * AD_ * 2);
  u16* Y_hi   = (u16*)carve((size_t)BB_ * FP_ * 2);   // fp16 bits
  u16* Y_lo   = (u16*)carve((size_t)BB_ * FP_ * 2);   // fp16 bits (unused by big gemm)
  float* cvec = (float*)carve((size_t)BB_ * 4);

  // 1) split inputs to bf16 hi/lo (W_temp also transposed to [FP][A])
  conv_hilo_k<<<(BB_ * FP_ / 4 + 255) / 256, 256, 0, stream>>>(m, m_hi, m_lo, BB_ * FP_);
  conv_hilo_k<<<(AD_ * FP_ / 4 + 255) / 256, 256, 0, stream>>>(Wmol, wm_hi, wm_lo, AD_ * FP_);
  conv_hilo_T_k<<<dim3(FP_ / 32, AD_ / 32), dim3(32, 8), 0, stream>>>(Wtmp, wtT_hi, wtT_lo, AD_, FP_);

  // 2) Xi = m @ W_mol^T + b_mol   [512 x 1024], K=2048  (fp32 + bf16 hi/lo out)
  gemm_hilo<64, 64, 2, 2, 1><<<dim3(BB_ / 64, AD_ / 64), 256, 0, stream>>>(
      m_hi, m_lo, wm_hi, wm_lo, BB_, AD_, FP_,
      Xi, Xi_hi, Xi_lo, bmol);

  // 3) c[b] = Xi[b,:] . b_temp
  dot_rows_k<<<BB_ / 4, 256, 0, stream>>>(Xi, btmp, cvec, AD_);

  // 4) Y = Xi @ W_temp   [512 x 2048], K=1024  -> fp16 hi/lo (big gemm uses hi only)
  gemm_hilo<64, 64, 2, 2, 2><<<dim3(BB_ / 64, FP_ / 64), 256, 0, stream>>>(
      Xi_hi, Xi_lo, wtT_hi, wtT_lo, BB_, FP_, AD_,
      nullptr, Y_hi, Y_lo, nullptr);

  // 5) out = BETA * (Y @ templates^T + c)   [512 x 50000], K=2048
  //    400 blocks = 8 XCD x (2 M-tiles x 25 strip-slots); 8 masked. 1 block/CU.
  gemm_big<<<400, 512, 0, stream>>>(Y_hi, tpl, out, cvec, BETA_);
}

// Round 15
// 247.580 us; speedup vs baseline: 6.6331x; 1.0377x over previous
//
#include <hip/hip_runtime.h>
#include <cstdint>
#include <cstddef>

typedef __attribute__((ext_vector_type(8))) short short8;     // 8 x 16-bit (4 VGPRs)
typedef __attribute__((ext_vector_type(8))) _Float16 f16x8;   // fp16 MFMA frag
typedef __attribute__((ext_vector_type(4))) float f32x4;
typedef __attribute__((ext_vector_type(4))) unsigned short u16x4;
typedef unsigned short u16;

#define FP_  2048
#define AD_  1024
#define BB_  512
#define TT_  50000
#define BETA_ 0.125f

// ---------- fp32 -> bf16 (RNE) helpers ----------
__device__ __forceinline__ u16 f2bf(float x){
  uint32_t u = __builtin_bit_cast(uint32_t, x);
  u = (u + 0x7fffu + ((u >> 16) & 1u)) >> 16;
  return (u16)u;
}
__device__ __forceinline__ float bf2f(u16 h){
  uint32_t u = ((uint32_t)h) << 16;
  return __builtin_bit_cast(float, u);
}
__device__ __forceinline__ u16 f2h_bits(float x){
  _Float16 h = (_Float16)x;            // RNE
  return __builtin_bit_cast(u16, h);
}
__device__ __forceinline__ unsigned int pkrtz_u32(float a, float b){
  return __builtin_bit_cast(unsigned int, __builtin_amdgcn_cvt_pkrtz(a, b));
}

// ---------- async global->LDS, 16B per lane ----------
__device__ __forceinline__ void gload_lds16(const void* g, void* l){
  __builtin_amdgcn_global_load_lds((const __attribute__((address_space(1))) void*)g,
                                   (__attribute__((address_space(3))) void*)l,
                                   16, 0, 0);
}

#define SB   __builtin_amdgcn_s_barrier()
#define SCH  __builtin_amdgcn_sched_barrier(0)
#define WAIT_LGKM0 asm volatile("s_waitcnt lgkmcnt(0)" ::: "memory")
#define WAIT_VM(n) asm volatile("s_waitcnt vmcnt(" #n ")" ::: "memory")

// ---------- elementwise fp32 -> (hi,lo) bf16 ----------
__global__ void conv_hilo_k(const float* __restrict__ src, u16* __restrict__ hi,
                            u16* __restrict__ lo, int n){
  int i = (blockIdx.x * blockDim.x + threadIdx.x) * 4;
  if (i >= n) return;
  f32x4 v = *reinterpret_cast<const f32x4*>(src + i);
  u16x4 h, l;
  #pragma unroll
  for (int e = 0; e < 4; ++e){
    float x = v[e];
    u16 hs = f2bf(x);
    h[e] = hs;
    l[e] = f2bf(x - bf2f(hs));
  }
  *reinterpret_cast<u16x4*>(hi + i) = h;
  *reinterpret_cast<u16x4*>(lo + i) = l;
}

// ---------- W[R][C] -> out[C][R] with hi/lo split (LDS tile transpose) ----------
__global__ void conv_hilo_T_k(const float* __restrict__ W, u16* __restrict__ hiT,
                              u16* __restrict__ loT, int R, int C){
  __shared__ float tile[32][33];
  int c0 = blockIdx.x * 32;
  int r0 = blockIdx.y * 32;
  int tx = threadIdx.x;   // 0..31
  int ty = threadIdx.y;   // 0..7
  #pragma unroll
  for (int i = 0; i < 32; i += 8)
    tile[ty + i][tx] = W[(size_t)(r0 + ty + i) * C + c0 + tx];
  __syncthreads();
  #pragma unroll
  for (int i = 0; i < 32; i += 8){
    float x = tile[tx][ty + i];              // = W[r0+tx][c0+ty+i]
    u16 hs = f2bf(x);
    size_t o = (size_t)(c0 + ty + i) * R + r0 + tx;   // out[f][a]
    hiT[o] = hs;
    loT[o] = f2bf(x - bf2f(hs));
  }
}

// ---------- c[b] = dot(Xi[b,:], b_temp) : one wave per row ----------
__global__ void dot_rows_k(const float* __restrict__ Xi, const float* __restrict__ bt,
                           float* __restrict__ c, int K){
  int row  = blockIdx.x * 4 + (threadIdx.x >> 6);
  int lane = threadIdx.x & 63;
  float s = 0.f;
  for (int a = lane; a < K; a += 64) s += Xi[(size_t)row * K + a] * bt[a];
  #pragma unroll
  for (int off = 32; off; off >>= 1) s += __shfl_down(s, off);
  if (lane == 0) c[row] = s;
}

// ---------- split-bf16 small GEMM: C = A·B^T + colBias (3-term hi/lo) ----------
// OUT16: 0=none, 1=bf16 hi/lo pair, 2=fp16 hi/lo pair
template<int TM, int TN, int FM, int FN, int OUT16>
__global__ __launch_bounds__(256, 2)
void gemm_hilo(const u16* __restrict__ Ahi, const u16* __restrict__ Alo,
               const u16* __restrict__ Bhi, const u16* __restrict__ Blo,
               int M, int N, int K,
               float* __restrict__ Cf, u16* __restrict__ Chi, u16* __restrict__ Clo,
               const float* __restrict__ colBias)
{
  constexpr int BK = 32;
  constexpr int WM = TM / (16 * FM);
  constexpr int WN = TN / (16 * FN);
  static_assert(WM * WN == 4, "4 waves / 256 threads");
  constexpr int BUFE = (2 * TM + 2 * TN) * BK;

  __shared__ __align__(16) u16 lds[2 * BUFE];

  const int m0 = blockIdx.x * TM;
  const int n0 = blockIdx.y * TN;

  const int tid  = threadIdx.x;
  const int w    = tid >> 6;
  const int lane = tid & 63;
  const int lr   = lane & 15;
  const int lg   = lane >> 4;
  const int wm   = w / WN;
  const int wn   = w % WN;

  const int rrA = tid >> 2;     // 0..63
  const int chA = tid & 3;      // 16B chunk

  short8 ra[2], rb[2];

  f32x4 acc[FM][FN];
  #pragma unroll
  for (int i = 0; i < FM; ++i)
    #pragma unroll
    for (int j = 0; j < FN; ++j)
      acc[i][j] = (f32x4){0.f, 0.f, 0.f, 0.f};

  auto stage_load = [&](int k0){
    int gm = m0 + rrA;
    ra[0] = *reinterpret_cast<const short8*>(Ahi + (size_t)gm * K + k0 + chA * 8);
    ra[1] = *reinterpret_cast<const short8*>(Alo + (size_t)gm * K + k0 + chA * 8);
    int gn = n0 + rrA; if (gn > N - 1) gn = N - 1;
    rb[0] = *reinterpret_cast<const short8*>(Bhi + (size_t)gn * K + k0 + chA * 8);
    rb[1] = *reinterpret_cast<const short8*>(Blo + (size_t)gn * K + k0 + chA * 8);
  };
  auto stage_store = [&](int buf){
    u16* As_hi = lds + buf * BUFE;
    u16* As_lo = As_hi + TM * BK;
    u16* Bs_hi = As_hi + 2 * TM * BK;
    u16* Bs_lo = As_hi + 2 * TM * BK + TN * BK;
    int row = rrA;
    int sw  = (chA ^ ((row >> 1) & 3)) << 3;
    *reinterpret_cast<short8*>(As_hi + row * BK + sw) = ra[0];
    *reinterpret_cast<short8*>(As_lo + row * BK + sw) = ra[1];
    *reinterpret_cast<short8*>(Bs_hi + row * BK + sw) = rb[0];
    *reinterpret_cast<short8*>(Bs_lo + row * BK + sw) = rb[1];
  };

  const int NT = K / BK;
  stage_load(0);
  stage_store(0);
  __syncthreads();

  int cur = 0;
  for (int t = 0; t < NT; ++t){
    const bool have_next = (t + 1 < NT);
    if (have_next) stage_load((t + 1) * BK);

    u16* As_hi = lds + cur * BUFE;
    u16* As_lo = As_hi + TM * BK;
    u16* Bs_hi = As_hi + 2 * TM * BK;
    u16* Bs_lo = As_hi + 2 * TM * BK + TN * BK;

    short8 ah[FM], al[FM], bh[FN], bl[FN];
    #pragma unroll
    for (int i = 0; i < FM; ++i){
      int row = wm * FM * 16 + i * 16 + lr;
      int off = row * BK + ((lg ^ ((row >> 1) & 3)) << 3);
      ah[i] = *reinterpret_cast<short8*>(As_hi + off);
      al[i] = *reinterpret_cast<short8*>(As_lo + off);
    }
    #pragma unroll
    for (int j = 0; j < FN; ++j){
      int row = wn * FN * 16 + j * 16 + lr;
      int off = row * BK + ((lg ^ ((row >> 1) & 3)) << 3);
      bh[j] = *reinterpret_cast<short8*>(Bs_hi + off);
      bl[j] = *reinterpret_cast<short8*>(Bs_lo + off);
    }
    #pragma unroll
    for (int i = 0; i < FM; ++i)
      #pragma unroll
      for (int j = 0; j < FN; ++j){
        acc[i][j] = __builtin_amdgcn_mfma_f32_16x16x32_bf16(ah[i], bh[j], acc[i][j], 0, 0, 0);
        acc[i][j] = __builtin_amdgcn_mfma_f32_16x16x32_bf16(ah[i], bl[j], acc[i][j], 0, 0, 0);
        acc[i][j] = __builtin_amdgcn_mfma_f32_16x16x32_bf16(al[i], bh[j], acc[i][j], 0, 0, 0);
      }

    if (have_next){
      __builtin_amdgcn_sched_barrier(0);
      stage_store(cur ^ 1);
      __syncthreads();
    }
    cur ^= 1;
  }

  #pragma unroll
  for (int i = 0; i < FM; ++i){
    int rbase = m0 + wm * FM * 16 + i * 16 + lg * 4;
    #pragma unroll
    for (int j = 0; j < FN; ++j){
      int gcol = n0 + wn * FN * 16 + j * 16 + lr;
      if (gcol < N){
        float cb = colBias ? colBias[gcol] : 0.f;
        #pragma unroll
        for (int r = 0; r < 4; ++r){
          int grow = rbase + r;
          float v = acc[i][j][r] + cb;
          size_t idx = (size_t)grow * N + gcol;
          if (Cf) Cf[idx] = v;
          if constexpr (OUT16 == 1){
            u16 hs = f2bf(v);
            Chi[idx] = hs;
            Clo[idx] = f2bf(v - bf2f(hs));
          } else if constexpr (OUT16 == 2){
            _Float16 h = (_Float16)v;
            Chi[idx] = __builtin_bit_cast(u16, h);
            Clo[idx] = f2h_bits(v - (float)h);
          }
        }
      }
    }
  }
}

// ---------- BIG GEMM: 256x256 8-phase template, GRAY-CODE phase order ----------
// out = alpha*(A·B^T + rowAdd). A = Y fp16 [512][2048] (L2-res., global_load_lds);
// B = fp32 templates, reg-staged 1.5 K-tiles ahead, pkrtz-published into the
// NEXT dbuf slot during phases B/C.
// 512 thr = 8 waves (2M x 4N), wave tile 128x64, acc 8x4 f32x4 frags.
// Phases per K-tile follow Gray order (0,0)->(0,1)->(1,1)->(1,0): each phase
// re-reads ONLY the changed operand -> 28 ds_read_b128/wave/tile (was 48).
// Ledger identical to R14 (issue order unchanged): entering T =
// [B0(T+1):4, B1(T+1):4]=8; steady waits all vmcnt(8); tail 8/4/0.
__global__ __launch_bounds__(512, 1)
void gemm_big(const u16* __restrict__ Ah,      // fp16 bits [512][2048]
              const float* __restrict__ Bf,    // [50000][2048]
              float* __restrict__ C,
              const float* __restrict__ rowAdd, float alpha)
{
  constexpr int K = FP_, NN = TT_;
  constexpr int NT = K / 64;                  // 32 K-tiles
  constexpr int KS = 8192;                    // u16 per ksub block (256x32)
  constexpr int BOFF = 16384;                 // B region offset (u16)
  constexpr int SLOT = 32768;                 // u16 per slot (64KB)

  __shared__ __align__(16) u16 lds[2 * SLOT]; // 128KB

  // XCD-bijective: 196 N-tiles of 256; xcd<4 own 25 strips, xcd>=4 own 24.
  int id  = blockIdx.x;
  int xcd = id & 7;
  int g   = id >> 3;          // 0..49
  int mt  = g & 1;            // 2 M-tiles of 256
  int sg  = g >> 1;           // 0..24
  int strips = (xcd < 4) ? 25 : 24;
  if (sg >= strips) return;
  int nt = ((xcd < 4) ? xcd * 25 : 100 + (xcd - 4) * 24) + sg;   // 0..195
  const int m0 = mt * 256;
  const int n0 = nt * 256;

  const int tid  = threadIdx.x;     // 0..511
  const int w    = tid >> 6;        // 0..7
  const int lane = tid & 63;
  const int lr   = lane & 15;
  const int lg   = lane >> 4;
  const int wm   = w >> 2;          // 0..1 (128-row band)
  const int wn   = w & 3;           // 0..3 (64-col band)

  // ---- A: global_load_lds, 2 calls per half (ks=0,1), linear dest ----
  auto glA = [&](u16* sp_, int Tt, int h){
    int rl = lane >> 2;             // 0..15
    int cc = lane & 3;              // 16B chunk of 64B row
    int row = h * 128 + w * 16 + rl;
    #pragma unroll
    for (int ks = 0; ks < 2; ++ks){
      const u16* src = Ah + (size_t)(m0 + row) * K + Tt * 64 + ks * 32
                     + ((cc ^ ((row >> 1) & 3)) << 3);
      gload_lds16(src, sp_ + ks * KS + (size_t)(h * 128 + w * 16) * 32);
    }
  };
  // ---- B: 4 coalesced f32x4 loads per thread per half ----
  auto issueB = [&](int Tt, int h, f32x4 (&rb)[4]){
    #pragma unroll
    for (int p = 0; p < 4; ++p){
      int rl = h * 128 + p * 32 + (tid >> 4);
      int gn = n0 + rl; if (gn > NN - 1) gn = NN - 1;
      rb[p] = *reinterpret_cast<const f32x4*>(Bf + (size_t)gn * K + Tt * 64 + (tid & 15) * 4);
    }
  };
  auto publishB = [&](u16* sp_, int h, f32x4 (&rb)[4]){
    int fch = tid & 15;
    int ks  = fch >> 3;
    int c16 = (fch & 7) >> 1;
    int hf  = fch & 1;
    #pragma unroll
    for (int p = 0; p < 4; ++p){
      int row = h * 128 + p * 32 + (tid >> 4);
      uint2 hv;
      hv.x = pkrtz_u32(rb[p][0], rb[p][1]);
      hv.y = pkrtz_u32(rb[p][2], rb[p][3]);
      int phys = c16 ^ ((row >> 1) & 3);
      *reinterpret_cast<uint2*>(sp_ + BOFF + ks * KS + row * 32 + phys * 8 + hf * 4) = hv;
    }
  };

  f32x4 acc[8][4];
  #pragma unroll
  for (int i = 0; i < 8; ++i)
    #pragma unroll
    for (int j = 0; j < 4; ++j)
      acc[i][j] = (f32x4){0.f, 0.f, 0.f, 0.f};

  f32x4 rbB0[4], rbB1[4];           // B-half reg sets (static names)
  f16x8 pa[4][2], pb[2][2];         // live fragment registers (Gray-reused)

#define READ_PA(SP, MH)                                                        \
  _Pragma("unroll")                                                            \
  for (int ii = 0; ii < 4; ++ii){                                              \
    int row_ = wm * 128 + ((MH) * 4 + ii) * 16 + lr;                           \
    _Pragma("unroll")                                                          \
    for (int ks_ = 0; ks_ < 2; ++ks_)                                          \
      pa[ii][ks_] = __builtin_bit_cast(f16x8, *reinterpret_cast<short8*>(      \
        (SP) + ks_ * KS + row_ * 32 + ((lg ^ ((row_ >> 1) & 3)) << 3)));       \
  }

#define READ_PB(SP, NH)                                                        \
  _Pragma("unroll")                                                            \
  for (int jj = 0; jj < 2; ++jj){                                              \
    int row_ = wn * 64 + ((NH) * 2 + jj) * 16 + lr;                            \
    _Pragma("unroll")                                                          \
    for (int ks_ = 0; ks_ < 2; ++ks_)                                          \
      pb[jj][ks_] = __builtin_bit_cast(f16x8, *reinterpret_cast<short8*>(      \
        (SP) + BOFF + ks_ * KS + row_ * 32 + ((lg ^ ((row_ >> 1) & 3)) << 3)));\
  }

#define MMA(MH, NH)                                                            \
  __builtin_amdgcn_s_setprio(1);                                               \
  _Pragma("unroll")                                                            \
  for (int ii = 0; ii < 4; ++ii)                                               \
    _Pragma("unroll")                                                          \
    for (int jj = 0; jj < 2; ++jj){                                            \
      acc[(MH)*4+ii][(NH)*2+jj] = __builtin_amdgcn_mfma_f32_16x16x32_f16(      \
          pa[ii][0], pb[jj][0], acc[(MH)*4+ii][(NH)*2+jj], 0, 0, 0);           \
      acc[(MH)*4+ii][(NH)*2+jj] = __builtin_amdgcn_mfma_f32_16x16x32_f16(      \
          pa[ii][1], pb[jj][1], acc[(MH)*4+ii][(NH)*2+jj], 0, 0, 0);           \
    }                                                                          \
  __builtin_amdgcn_s_setprio(0);

  // ---- prologue: tile0 staged+published into slot0; B(1) sets in flight ----
  glA(lds, 0, 0);  glA(lds, 0, 1);    // 4 entries
  SCH;
  issueB(0, 0, rbB0);                 // 8
  issueB(0, 1, rbB1);                 // 12
  SCH;
  WAIT_VM(4); SCH;                    // A(0) + B0(0) retired
  publishB(lds, 0, rbB0);
  WAIT_VM(0); SCH;                    // B1(0) retired
  publishB(lds, 1, rbB1);
  SCH;
  issueB(1, 0, rbB0);                 // 4
  issueB(1, 1, rbB1);                 // 8
  WAIT_LGKM0;
  SB; SCH;
  // entering T=0: outstanding [B0(1):4, B1(1):4] = 8  (invariant)

  for (int T = 0; T < NT; ++T){
    u16* sp  = lds + (size_t)(T & 1) * SLOT;
    u16* spn = lds + (size_t)((T + 1) & 1) * SLOT;
    const bool hasN  = (T + 1 < NT);
    const bool hasNN = (T + 2 < NT);

    // ---- phase A: quadrant (0,0) — read pa0 + pb0; stage A0(T+1) ----
    READ_PA(sp, 0);
    READ_PB(sp, 0);
    if (hasN) glA(spn, T + 1, 0);
    SB; WAIT_LGKM0; SCH;
    MMA(0, 0);
    SB;

    // ---- phase B: quadrant (0,1) — read pb1 only; stage A1(T+1);
    //      publish B0(T+1); issue B0(T+2) ----
    READ_PB(sp, 1);
    if (hasN){
      glA(spn, T + 1, 1);
      SCH;
      WAIT_VM(8); SCH;                         // B0(T+1) retired
      publishB(spn, 0, rbB0);
      if (hasNN){ issueB(T + 2, 0, rbB0); SCH; }
    }
    SB; WAIT_LGKM0; SCH;
    MMA(0, 1);
    SB;

    // ---- phase C: quadrant (1,1) — read pa1 only (pb1 reused);
    //      publish B1(T+1); issue B1(T+2) ----
    READ_PA(sp, 1);
    if (hasN){
      if (hasNN) { WAIT_VM(8); } else { WAIT_VM(4); }   // B1(T+1) retired
      SCH;
      publishB(spn, 1, rbB1);
      if (hasNN){ issueB(T + 2, 1, rbB1); SCH; }
    }
    SB; WAIT_LGKM0; SCH;
    MMA(1, 1);
    SB;

    // ---- phase D: quadrant (1,0) — read pb0 only (pa1 reused);
    //      confirm A(T+1) landed ----
    READ_PB(sp, 0);
    if (hasN){
      if (hasNN) { WAIT_VM(8); } else { WAIT_VM(0); }   // A(T+1) in LDS
      SCH;
    }
    SB; WAIT_LGKM0; SCH;
    MMA(1, 0);
    SB;
  }

#undef READ_PA
#undef READ_PB
#undef MMA

  // ---- epilogue: row=(lane>>4)*4+reg (A idx), col=lane&15 (B idx) ----
  #pragma unroll
  for (int i = 0; i < 8; ++i){
    int rbase = m0 + wm * 128 + i * 16 + lg * 4;
    #pragma unroll
    for (int j = 0; j < 4; ++j){
      int gcol = n0 + wn * 64 + j * 16 + lr;
      if (gcol < NN){
        #pragma unroll
        for (int r = 0; r < 4; ++r){
          int grow = rbase + r;
          float v = (acc[i][j][r] + rowAdd[grow]) * alpha;
          C[(size_t)grow * NN + gcol] = v;
        }
      }
    }
  }
}

extern "C" void kernel_launch(void* const* d_in, const int* in_sizes, int n_in,
                              void* d_out, int out_size, void* d_ws, size_t ws_size,
                              hipStream_t stream){
  (void)in_sizes; (void)n_in; (void)out_size; (void)ws_size;
  const float* m    = (const float*)d_in[0];   // [512][2048]
  const float* tpl  = (const float*)d_in[1];   // [50000][2048]
  const float* Wmol = (const float*)d_in[2];   // [1024][2048]
  const float* bmol = (const float*)d_in[3];   // [1024]
  const float* Wtmp = (const float*)d_in[4];   // [1024][2048]
  const float* btmp = (const float*)d_in[5];   // [1024]
  float* out = (float*)d_out;                  // [512][50000]

  uint8_t* wp = (uint8_t*)d_ws;
  auto carve = [&](size_t bytes) -> void* {
    void* p = (void*)wp;
    wp += (bytes + 255) & ~(size_t)255;
    return p;
  };
  u16* m_hi   = (u16*)carve((size_t)BB_ * FP_ * 2);
  u16* m_lo   = (u16*)carve((size_t)BB_ * FP_ * 2);
  u16* wm_hi  = (u16*)carve((size_t)AD_ * FP_ * 2);
  u16* wm_lo  = (u16*)carve((size_t)AD_ * FP_ * 2);
  u16* wtT_hi = (u16*)carve((size_t)FP_ * AD_ * 2);
  u16* wtT_lo = (u16*)carve((size_t)FP_ * AD_ * 2);
  float* Xi   = (float*)carve((size_t)BB_ * AD_ * 4);
  u16* Xi_hi  = (u16*)carve((size_t)BB_ * AD_ * 2);
  u16* Xi_lo  = (u16*)carve((size_t)BB_ * AD_ * 2);
  u16* Y_hi   = (u16*)carve((size_t)BB_ * FP_ * 2);   // fp16 bits
  u16* Y_lo   = (u16*)carve((size_t)BB_ * FP_ * 2);   // fp16 bits (unused by big gemm)
  float* cvec = (float*)carve((size_t)BB_ * 4);

  // 1) split inputs to bf16 hi/lo (W_temp also transposed to [FP][A])
  conv_hilo_k<<<(BB_ * FP_ / 4 + 255) / 256, 256, 0, stream>>>(m, m_hi, m_lo, BB_ * FP_);
  conv_hilo_k<<<(AD_ * FP_ / 4 + 255) / 256, 256, 0, stream>>>(Wmol, wm_hi, wm_lo, AD_ * FP_);
  conv_hilo_T_k<<<dim3(FP_ / 32, AD_ / 32), dim3(32, 8), 0, stream>>>(Wtmp, wtT_hi, wtT_lo, AD_, FP_);

  // 2) Xi = m @ W_mol^T + b_mol   [512 x 1024], K=2048  (fp32 + bf16 hi/lo out)
  gemm_hilo<64, 64, 2, 2, 1><<<dim3(BB_ / 64, AD_ / 64), 256, 0, stream>>>(
      m_hi, m_lo, wm_hi, wm_lo, BB_, AD_, FP_,
      Xi, Xi_hi, Xi_lo, bmol);

  // 3) c[b] = Xi[b,:] . b_temp
  dot_rows_k<<<BB_ / 4, 256, 0, stream>>>(Xi, btmp, cvec, AD_);

  // 4) Y = Xi @ W_temp   [512 x 2048], K=1024  -> fp16 hi/lo (big gemm uses hi only)
  gemm_hilo<64, 64, 2, 2, 2><<<dim3(BB_ / 64, FP_ / 64), 256, 0, stream>>>(
      Xi_hi, Xi_lo, wtT_hi, wtT_lo, BB_, FP_, AD_,
      nullptr, Y_hi, Y_lo, nullptr);

  // 5) out = BETA * (Y @ templates^T + c)   [512 x 50000], K=2048
  //    400 blocks = 8 XCD x (2 M-tiles x 25 strip-slots); 8 masked. 1 block/CU.
  gemm_big<<<400, 512, 0, stream>>>(Y_hi, tpl, out, cvec, BETA_);
}

// Round 16
// 237.231 us; speedup vs baseline: 6.9225x; 1.0436x over previous
//
#include <hip/hip_runtime.h>
#include <cstdint>
#include <cstddef>

typedef __attribute__((ext_vector_type(8))) short short8;     // 8 x 16-bit (4 VGPRs)
typedef __attribute__((ext_vector_type(8))) _Float16 f16x8;   // fp16 MFMA frag
typedef __attribute__((ext_vector_type(4))) float f32x4;
typedef __attribute__((ext_vector_type(4))) unsigned short u16x4;
typedef unsigned short u16;

#define FP_  2048
#define AD_  1024
#define BB_  512
#define TT_  50000
#define BETA_ 0.125f

// ---------- fp32 -> bf16 (RNE) helpers ----------
__device__ __forceinline__ u16 f2bf(float x){
  uint32_t u = __builtin_bit_cast(uint32_t, x);
  u = (u + 0x7fffu + ((u >> 16) & 1u)) >> 16;
  return (u16)u;
}
__device__ __forceinline__ float bf2f(u16 h){
  uint32_t u = ((uint32_t)h) << 16;
  return __builtin_bit_cast(float, u);
}
__device__ __forceinline__ u16 f2h_bits(float x){
  _Float16 h = (_Float16)x;            // RNE
  return __builtin_bit_cast(u16, h);
}
__device__ __forceinline__ unsigned int pkrtz_u32(float a, float b){
  return __builtin_bit_cast(unsigned int, __builtin_amdgcn_cvt_pkrtz(a, b));
}

// ---------- async global->LDS, 16B per lane ----------
__device__ __forceinline__ void gload_lds16(const void* g, void* l){
  __builtin_amdgcn_global_load_lds((const __attribute__((address_space(1))) void*)g,
                                   (__attribute__((address_space(3))) void*)l,
                                   16, 0, 0);
}

#define SB   __builtin_amdgcn_s_barrier()
#define SCH  __builtin_amdgcn_sched_barrier(0)
#define WAIT_LGKM0 asm volatile("s_waitcnt lgkmcnt(0)" ::: "memory")
#define WAIT_VM(n) asm volatile("s_waitcnt vmcnt(" #n ")" ::: "memory")

// ---------- elementwise fp32 -> (hi,lo) bf16 ----------
__global__ void conv_hilo_k(const float* __restrict__ src, u16* __restrict__ hi,
                            u16* __restrict__ lo, int n){
  int i = (blockIdx.x * blockDim.x + threadIdx.x) * 4;
  if (i >= n) return;
  f32x4 v = *reinterpret_cast<const f32x4*>(src + i);
  u16x4 h, l;
  #pragma unroll
  for (int e = 0; e < 4; ++e){
    float x = v[e];
    u16 hs = f2bf(x);
    h[e] = hs;
    l[e] = f2bf(x - bf2f(hs));
  }
  *reinterpret_cast<u16x4*>(hi + i) = h;
  *reinterpret_cast<u16x4*>(lo + i) = l;
}

// ---------- W[R][C] -> out[C][R] with hi/lo split (LDS tile transpose) ----------
__global__ void conv_hilo_T_k(const float* __restrict__ W, u16* __restrict__ hiT,
                              u16* __restrict__ loT, int R, int C){
  __shared__ float tile[32][33];
  int c0 = blockIdx.x * 32;
  int r0 = blockIdx.y * 32;
  int tx = threadIdx.x;   // 0..31
  int ty = threadIdx.y;   // 0..7
  #pragma unroll
  for (int i = 0; i < 32; i += 8)
    tile[ty + i][tx] = W[(size_t)(r0 + ty + i) * C + c0 + tx];
  __syncthreads();
  #pragma unroll
  for (int i = 0; i < 32; i += 8){
    float x = tile[tx][ty + i];              // = W[r0+tx][c0+ty+i]
    u16 hs = f2bf(x);
    size_t o = (size_t)(c0 + ty + i) * R + r0 + tx;   // out[f][a]
    hiT[o] = hs;
    loT[o] = f2bf(x - bf2f(hs));
  }
}

// ---------- c[b] = dot(Xi[b,:], b_temp) : one wave per row ----------
__global__ void dot_rows_k(const float* __restrict__ Xi, const float* __restrict__ bt,
                           float* __restrict__ c, int K){
  int row  = blockIdx.x * 4 + (threadIdx.x >> 6);
  int lane = threadIdx.x & 63;
  float s = 0.f;
  for (int a = lane; a < K; a += 64) s += Xi[(size_t)row * K + a] * bt[a];
  #pragma unroll
  for (int off = 32; off; off >>= 1) s += __shfl_down(s, off);
  if (lane == 0) c[row] = s;
}

// ---------- split-bf16 small GEMM: C = A·B^T + colBias (3-term hi/lo) ----------
// OUT16: 0=none, 1=bf16 hi/lo pair, 2=fp16 hi/lo pair
template<int TM, int TN, int FM, int FN, int OUT16>
__global__ __launch_bounds__(256, 2)
void gemm_hilo(const u16* __restrict__ Ahi, const u16* __restrict__ Alo,
               const u16* __restrict__ Bhi, const u16* __restrict__ Blo,
               int M, int N, int K,
               float* __restrict__ Cf, u16* __restrict__ Chi, u16* __restrict__ Clo,
               const float* __restrict__ colBias)
{
  constexpr int BK = 32;
  constexpr int WM = TM / (16 * FM);
  constexpr int WN = TN / (16 * FN);
  static_assert(WM * WN == 4, "4 waves / 256 threads");
  constexpr int BUFE = (2 * TM + 2 * TN) * BK;

  __shared__ __align__(16) u16 lds[2 * BUFE];

  const int m0 = blockIdx.x * TM;
  const int n0 = blockIdx.y * TN;

  const int tid  = threadIdx.x;
  const int w    = tid >> 6;
  const int lane = tid & 63;
  const int lr   = lane & 15;
  const int lg   = lane >> 4;
  const int wm   = w / WN;
  const int wn   = w % WN;

  const int rrA = tid >> 2;     // 0..63
  const int chA = tid & 3;      // 16B chunk

  short8 ra[2], rb[2];

  f32x4 acc[FM][FN];
  #pragma unroll
  for (int i = 0; i < FM; ++i)
    #pragma unroll
    for (int j = 0; j < FN; ++j)
      acc[i][j] = (f32x4){0.f, 0.f, 0.f, 0.f};

  auto stage_load = [&](int k0){
    int gm = m0 + rrA;
    ra[0] = *reinterpret_cast<const short8*>(Ahi + (size_t)gm * K + k0 + chA * 8);
    ra[1] = *reinterpret_cast<const short8*>(Alo + (size_t)gm * K + k0 + chA * 8);
    int gn = n0 + rrA; if (gn > N - 1) gn = N - 1;
    rb[0] = *reinterpret_cast<const short8*>(Bhi + (size_t)gn * K + k0 + chA * 8);
    rb[1] = *reinterpret_cast<const short8*>(Blo + (size_t)gn * K + k0 + chA * 8);
  };
  auto stage_store = [&](int buf){
    u16* As_hi = lds + buf * BUFE;
    u16* As_lo = As_hi + TM * BK;
    u16* Bs_hi = As_hi + 2 * TM * BK;
    u16* Bs_lo = As_hi + 2 * TM * BK + TN * BK;
    int row = rrA;
    int sw  = (chA ^ ((row >> 1) & 3)) << 3;
    *reinterpret_cast<short8*>(As_hi + row * BK + sw) = ra[0];
    *reinterpret_cast<short8*>(As_lo + row * BK + sw) = ra[1];
    *reinterpret_cast<short8*>(Bs_hi + row * BK + sw) = rb[0];
    *reinterpret_cast<short8*>(Bs_lo + row * BK + sw) = rb[1];
  };

  const int NT = K / BK;
  stage_load(0);
  stage_store(0);
  __syncthreads();

  int cur = 0;
  for (int t = 0; t < NT; ++t){
    const bool have_next = (t + 1 < NT);
    if (have_next) stage_load((t + 1) * BK);

    u16* As_hi = lds + cur * BUFE;
    u16* As_lo = As_hi + TM * BK;
    u16* Bs_hi = As_hi + 2 * TM * BK;
    u16* Bs_lo = As_hi + 2 * TM * BK + TN * BK;

    short8 ah[FM], al[FM], bh[FN], bl[FN];
    #pragma unroll
    for (int i = 0; i < FM; ++i){
      int row = wm * FM * 16 + i * 16 + lr;
      int off = row * BK + ((lg ^ ((row >> 1) & 3)) << 3);
      ah[i] = *reinterpret_cast<short8*>(As_hi + off);
      al[i] = *reinterpret_cast<short8*>(As_lo + off);
    }
    #pragma unroll
    for (int j = 0; j < FN; ++j){
      int row = wn * FN * 16 + j * 16 + lr;
      int off = row * BK + ((lg ^ ((row >> 1) & 3)) << 3);
      bh[j] = *reinterpret_cast<short8*>(Bs_hi + off);
      bl[j] = *reinterpret_cast<short8*>(Bs_lo + off);
    }
    #pragma unroll
    for (int i = 0; i < FM; ++i)
      #pragma unroll
      for (int j = 0; j < FN; ++j){
        acc[i][j] = __builtin_amdgcn_mfma_f32_16x16x32_bf16(ah[i], bh[j], acc[i][j], 0, 0, 0);
        acc[i][j] = __builtin_amdgcn_mfma_f32_16x16x32_bf16(ah[i], bl[j], acc[i][j], 0, 0, 0);
        acc[i][j] = __builtin_amdgcn_mfma_f32_16x16x32_bf16(al[i], bh[j], acc[i][j], 0, 0, 0);
      }

    if (have_next){
      __builtin_amdgcn_sched_barrier(0);
      stage_store(cur ^ 1);
      __syncthreads();
    }
    cur ^= 1;
  }

  #pragma unroll
  for (int i = 0; i < FM; ++i){
    int rbase = m0 + wm * FM * 16 + i * 16 + lg * 4;
    #pragma unroll
    for (int j = 0; j < FN; ++j){
      int gcol = n0 + wn * FN * 16 + j * 16 + lr;
      if (gcol < N){
        float cb = colBias ? colBias[gcol] : 0.f;
        #pragma unroll
        for (int r = 0; r < 4; ++r){
          int grow = rbase + r;
          float v = acc[i][j][r] + cb;
          size_t idx = (size_t)grow * N + gcol;
          if (Cf) Cf[idx] = v;
          if constexpr (OUT16 == 1){
            u16 hs = f2bf(v);
            Chi[idx] = hs;
            Clo[idx] = f2bf(v - bf2f(hs));
          } else if constexpr (OUT16 == 2){
            _Float16 h = (_Float16)v;
            Chi[idx] = __builtin_bit_cast(u16, h);
            Clo[idx] = f2h_bits(v - (float)h);
          }
        }
      }
    }
  }
}

// ---------- BIG GEMM: 256x256 Gray-code phases, DE-LOCKSTEPPED ----------
// out = alpha*(A·B^T + rowAdd). A = Y fp16 [512][2048] (L2-res., global_load_lds);
// B = fp32 templates, reg-staged 1.5 K-tiles ahead, pkrtz-published into the
// NEXT dbuf slot during phases B/C.
// De-lockstep: NO intra-tile barriers. Within tile T all frag reads hit the
// stable slot sp; all staging targets spn (not read until T+1). Ordering is
// enforced per-wave by lgkmcnt(0) before each MMA + the vmcnt ledger, and
// block-wide by ONE boundary s_barrier per K-tile (reads-of-sp done; spn
// staged/visible). Waves de-phase so LDS drain overlaps other waves' MFMA.
// Ledger unchanged from R15: entering T = [B0(T+1):4, B1(T+1):4] = 8;
// phase B VM(8), phase C VM(8|4), phase D VM(8|0).
__global__ __launch_bounds__(512, 1)
void gemm_big(const u16* __restrict__ Ah,      // fp16 bits [512][2048]
              const float* __restrict__ Bf,    // [50000][2048]
              float* __restrict__ C,
              const float* __restrict__ rowAdd, float alpha)
{
  constexpr int K = FP_, NN = TT_;
  constexpr int NT = K / 64;                  // 32 K-tiles
  constexpr int KS = 8192;                    // u16 per ksub block (256x32)
  constexpr int BOFF = 16384;                 // B region offset (u16)
  constexpr int SLOT = 32768;                 // u16 per slot (64KB)

  __shared__ __align__(16) u16 lds[2 * SLOT]; // 128KB

  // XCD-bijective: 196 N-tiles of 256; xcd<4 own 25 strips, xcd>=4 own 24.
  int id  = blockIdx.x;
  int xcd = id & 7;
  int g   = id >> 3;          // 0..49
  int mt  = g & 1;            // 2 M-tiles of 256
  int sg  = g >> 1;           // 0..24
  int strips = (xcd < 4) ? 25 : 24;
  if (sg >= strips) return;
  int nt = ((xcd < 4) ? xcd * 25 : 100 + (xcd - 4) * 24) + sg;   // 0..195
  const int m0 = mt * 256;
  const int n0 = nt * 256;

  const int tid  = threadIdx.x;     // 0..511
  const int w    = tid >> 6;        // 0..7
  const int lane = tid & 63;
  const int lr   = lane & 15;
  const int lg   = lane >> 4;
  const int wm   = w >> 2;          // 0..1 (128-row band)
  const int wn   = w & 3;           // 0..3 (64-col band)

  // ---- A: global_load_lds, 2 calls per half (ks=0,1), linear dest ----
  auto glA = [&](u16* sp_, int Tt, int h){
    int rl = lane >> 2;             // 0..15
    int cc = lane & 3;              // 16B chunk of 64B row
    int row = h * 128 + w * 16 + rl;
    #pragma unroll
    for (int ks = 0; ks < 2; ++ks){
      const u16* src = Ah + (size_t)(m0 + row) * K + Tt * 64 + ks * 32
                     + ((cc ^ ((row >> 1) & 3)) << 3);
      gload_lds16(src, sp_ + ks * KS + (size_t)(h * 128 + w * 16) * 32);
    }
  };
  // ---- B: 4 coalesced f32x4 loads per thread per half ----
  auto issueB = [&](int Tt, int h, f32x4 (&rb)[4]){
    #pragma unroll
    for (int p = 0; p < 4; ++p){
      int rl = h * 128 + p * 32 + (tid >> 4);
      int gn = n0 + rl; if (gn > NN - 1) gn = NN - 1;
      rb[p] = *reinterpret_cast<const f32x4*>(Bf + (size_t)gn * K + Tt * 64 + (tid & 15) * 4);
    }
  };
  auto publishB = [&](u16* sp_, int h, f32x4 (&rb)[4]){
    int fch = tid & 15;
    int ks  = fch >> 3;
    int c16 = (fch & 7) >> 1;
    int hf  = fch & 1;
    #pragma unroll
    for (int p = 0; p < 4; ++p){
      int row = h * 128 + p * 32 + (tid >> 4);
      uint2 hv;
      hv.x = pkrtz_u32(rb[p][0], rb[p][1]);
      hv.y = pkrtz_u32(rb[p][2], rb[p][3]);
      int phys = c16 ^ ((row >> 1) & 3);
      *reinterpret_cast<uint2*>(sp_ + BOFF + ks * KS + row * 32 + phys * 8 + hf * 4) = hv;
    }
  };

  f32x4 acc[8][4];
  #pragma unroll
  for (int i = 0; i < 8; ++i)
    #pragma unroll
    for (int j = 0; j < 4; ++j)
      acc[i][j] = (f32x4){0.f, 0.f, 0.f, 0.f};

  f32x4 rbB0[4], rbB1[4];           // B-half reg sets (static names)
  f16x8 pa[4][2], pb[2][2];         // live fragment registers (Gray-reused)

#define READ_PA(SP, MH)                                                        \
  _Pragma("unroll")                                                            \
  for (int ii = 0; ii < 4; ++ii){                                              \
    int row_ = wm * 128 + ((MH) * 4 + ii) * 16 + lr;                           \
    _Pragma("unroll")                                                          \
    for (int ks_ = 0; ks_ < 2; ++ks_)                                          \
      pa[ii][ks_] = __builtin_bit_cast(f16x8, *reinterpret_cast<short8*>(      \
        (SP) + ks_ * KS + row_ * 32 + ((lg ^ ((row_ >> 1) & 3)) << 3)));       \
  }

#define READ_PB(SP, NH)                                                        \
  _Pragma("unroll")                                                            \
  for (int jj = 0; jj < 2; ++jj){                                              \
    int row_ = wn * 64 + ((NH) * 2 + jj) * 16 + lr;                            \
    _Pragma("unroll")                                                          \
    for (int ks_ = 0; ks_ < 2; ++ks_)                                          \
      pb[jj][ks_] = __builtin_bit_cast(f16x8, *reinterpret_cast<short8*>(      \
        (SP) + BOFF + ks_ * KS + row_ * 32 + ((lg ^ ((row_ >> 1) & 3)) << 3)));\
  }

#define MMA(MH, NH)                                                            \
  __builtin_amdgcn_s_setprio(1);                                               \
  _Pragma("unroll")                                                            \
  for (int ii = 0; ii < 4; ++ii)                                               \
    _Pragma("unroll")                                                          \
    for (int jj = 0; jj < 2; ++jj){                                            \
      acc[(MH)*4+ii][(NH)*2+jj] = __builtin_amdgcn_mfma_f32_16x16x32_f16(      \
          pa[ii][0], pb[jj][0], acc[(MH)*4+ii][(NH)*2+jj], 0, 0, 0);           \
      acc[(MH)*4+ii][(NH)*2+jj] = __builtin_amdgcn_mfma_f32_16x16x32_f16(      \
          pa[ii][1], pb[jj][1], acc[(MH)*4+ii][(NH)*2+jj], 0, 0, 0);           \
    }                                                                          \
  __builtin_amdgcn_s_setprio(0);

  // ---- prologue: tile0 staged+published into slot0; B(1) sets in flight ----
  glA(lds, 0, 0);  glA(lds, 0, 1);    // 4 entries
  SCH;
  issueB(0, 0, rbB0);                 // 8
  issueB(0, 1, rbB1);                 // 12
  SCH;
  WAIT_VM(4); SCH;                    // A(0) + B0(0) retired
  publishB(lds, 0, rbB0);
  WAIT_VM(0); SCH;                    // B1(0) retired
  publishB(lds, 1, rbB1);
  SCH;
  issueB(1, 0, rbB0);                 // 4
  issueB(1, 1, rbB1);                 // 8
  WAIT_LGKM0;
  SB; SCH;
  // entering T=0: outstanding [B0(1):4, B1(1):4] = 8  (invariant)

  for (int T = 0; T < NT; ++T){
    u16* sp  = lds + (size_t)(T & 1) * SLOT;
    u16* spn = lds + (size_t)((T + 1) & 1) * SLOT;
    const bool hasN  = (T + 1 < NT);
    const bool hasNN = (T + 2 < NT);

    // ---- phase A: quadrant (0,0); stage A0(T+1) ----
    READ_PA(sp, 0);
    READ_PB(sp, 0);
    if (hasN) glA(spn, T + 1, 0);
    WAIT_LGKM0; SCH;
    MMA(0, 0);

    // ---- phase B: quadrant (0,1); stage A1(T+1); publish B0(T+1); issue B0(T+2) ----
    READ_PB(sp, 1);
    if (hasN){
      glA(spn, T + 1, 1);
      SCH;
      WAIT_VM(8); SCH;                         // B0(T+1) retired
      publishB(spn, 0, rbB0);
      if (hasNN){ issueB(T + 2, 0, rbB0); SCH; }
    }
    WAIT_LGKM0; SCH;
    MMA(0, 1);

    // ---- phase C: quadrant (1,1); publish B1(T+1); issue B1(T+2) ----
    READ_PA(sp, 1);
    if (hasN){
      if (hasNN) { WAIT_VM(8); } else { WAIT_VM(4); }   // B1(T+1) retired
      SCH;
      publishB(spn, 1, rbB1);
      if (hasNN){ issueB(T + 2, 1, rbB1); SCH; }
    }
    WAIT_LGKM0; SCH;
    MMA(1, 1);

    // ---- phase D: quadrant (1,0); confirm A(T+1) landed; boundary barrier ----
    READ_PB(sp, 0);
    if (hasN){
      if (hasNN) { WAIT_VM(8); } else { WAIT_VM(0); }   // A(T+1) in LDS
      SCH;
    }
    WAIT_LGKM0; SCH;
    MMA(1, 0);
    SCH;
    SB;                                // ONE barrier per K-tile (slot swap)
  }

#undef READ_PA
#undef READ_PB
#undef MMA

  // ---- epilogue: row=(lane>>4)*4+reg (A idx), col=lane&15 (B idx) ----
  #pragma unroll
  for (int i = 0; i < 8; ++i){
    int rbase = m0 + wm * 128 + i * 16 + lg * 4;
    #pragma unroll
    for (int j = 0; j < 4; ++j){
      int gcol = n0 + wn * 64 + j * 16 + lr;
      if (gcol < NN){
        #pragma unroll
        for (int r = 0; r < 4; ++r){
          int grow = rbase + r;
          float v = (acc[i][j][r] + rowAdd[grow]) * alpha;
          C[(size_t)grow * NN + gcol] = v;
        }
      }
    }
  }
}

extern "C" void kernel_launch(void* const* d_in, const int* in_sizes, int n_in,
                              void* d_out, int out_size, void* d_ws, size_t ws_size,
                              hipStream_t stream){
  (void)in_sizes; (void)n_in; (void)out_size; (void)ws_size;
  const float* m    = (const float*)d_in[0];   // [512][2048]
  const float* tpl  = (const float*)d_in[1];   // [50000][2048]
  const float* Wmol = (const float*)d_in[2];   // [1024][2048]
  const float* bmol = (const float*)d_in[3];   // [1024]
  const float* Wtmp = (const float*)d_in[4];   // [1024][2048]
  const float* btmp = (const float*)d_in[5];   // [1024]
  float* out = (float*)d_out;                  // [512][50000]

  uint8_t* wp = (uint8_t*)d_ws;
  auto carve = [&](size_t bytes) -> void* {
    void* p = (void*)wp;
    wp += (bytes + 255) & ~(size_t)255;
    return p;
  };
  u16* m_hi   = (u16*)carve((size_t)BB_ * FP_ * 2);
  u16* m_lo   = (u16*)carve((size_t)BB_ * FP_ * 2);
  u16* wm_hi  = (u16*)carve((size_t)AD_ * FP_ * 2);
  u16* wm_lo  = (u16*)carve((size_t)AD_ * FP_ * 2);
  u16* wtT_hi = (u16*)carve((size_t)FP_ * AD_ * 2);
  u16* wtT_lo = (u16*)carve((size_t)FP_ * AD_ * 2);
  float* Xi   = (float*)carve((size_t)BB_ * AD_ * 4);
  u16* Xi_hi  = (u16*)carve((size_t)BB_ * AD_ * 2);
  u16* Xi_lo  = (u16*)carve((size_t)BB_ * AD_ * 2);
  u16* Y_hi   = (u16*)carve((size_t)BB_ * FP_ * 2);   // fp16 bits
  u16* Y_lo   = (u16*)carve((size_t)BB_ * FP_ * 2);   // fp16 bits (unused by big gemm)
  float* cvec = (float*)carve((size_t)BB_ * 4);

  // 1) split inputs to bf16 hi/lo (W_temp also transposed to [FP][A])
  conv_hilo_k<<<(BB_ * FP_ / 4 + 255) / 256, 256, 0, stream>>>(m, m_hi, m_lo, BB_ * FP_);
  conv_hilo_k<<<(AD_ * FP_ / 4 + 255) / 256, 256, 0, stream>>>(Wmol, wm_hi, wm_lo, AD_ * FP_);
  conv_hilo_T_k<<<dim3(FP_ / 32, AD_ / 32), dim3(32, 8), 0, stream>>>(Wtmp, wtT_hi, wtT_lo, AD_, FP_);

  // 2) Xi = m @ W_mol^T + b_mol   [512 x 1024], K=2048  (fp32 + bf16 hi/lo out)
  gemm_hilo<64, 64, 2, 2, 1><<<dim3(BB_ / 64, AD_ / 64), 256, 0, stream>>>(
      m_hi, m_lo, wm_hi, wm_lo, BB_, AD_, FP_,
      Xi, Xi_hi, Xi_lo, bmol);

  // 3) c[b] = Xi[b,:] . b_temp
  dot_rows_k<<<BB_ / 4, 256, 0, stream>>>(Xi, btmp, cvec, AD_);

  // 4) Y = Xi @ W_temp   [512 x 2048], K=1024  -> fp16 hi/lo (big gemm uses hi only)
  gemm_hilo<64, 64, 2, 2, 2><<<dim3(BB_ / 64, FP_ / 64), 256, 0, stream>>>(
      Xi_hi, Xi_lo, wtT_hi, wtT_lo, BB_, FP_, AD_,
      nullptr, Y_hi, Y_lo, nullptr);

  // 5) out = BETA * (Y @ templates^T + c)   [512 x 50000], K=2048
  //    400 blocks = 8 XCD x (2 M-tiles x 25 strip-slots); 8 masked. 1 block/CU.
  gemm_big<<<400, 512, 0, stream>>>(Y_hi, tpl, out, cvec, BETA_);
}